// Round 4
// baseline (454.033 us; speedup 1.0000x reference)
//
#include <hip/hip_runtime.h>
#include <hip/hip_bf16.h>
#include <math.h>

typedef __hip_bfloat16 bf16;
typedef __bf16 bhalf;
typedef bhalf bhalf8 __attribute__((ext_vector_type(8)));
typedef float f32x4 __attribute__((ext_vector_type(4)));
typedef unsigned short u16;
typedef u16 u16x4 __attribute__((ext_vector_type(4)));
typedef u16 u16x8 __attribute__((ext_vector_type(8)));

#define D_MODEL   1024
#define D_STATE   64
#define HEADDIM   64
#define D_INNER   2048
#define NHEADS    32
#define CONV_DIM  2176
#define D_IN_PROJ 4256
#define FFN_DIM   4096
#define BSZ       2
#define SEQ       2048
#define NROWS     (BSZ*SEQ)
#define TC        64
#define NCH       (SEQ/TC)

#define AS1 __attribute__((address_space(1)))
#define AS3 __attribute__((address_space(3)))
__device__ __forceinline__ void load_lds16(const void* g, void* l) {
  __builtin_amdgcn_global_load_lds((AS1 void*)g, (AS3 void*)l, 16, 0, 0);
}

__device__ __forceinline__ float bf2f(u16 u) {
  return __uint_as_float(((unsigned)u) << 16);
}
__device__ __forceinline__ u16 f2bbits(float f) {
  bf16 h = __float2bfloat16(f);
  return *(u16*)&h;
}

// ---------------------------------------------------------------------------
// Normalize weight inputs to bf16 copies; vectorized. Each block self-detects
// the input dtype. Block 0 publishes the flag for downstream consumers.
// ---------------------------------------------------------------------------
#define NT 18
struct CvtArgs {
  const void* src[NT];
  void*       dst[NT];
  int ccum[NT + 1];
  int nel[NT];
};

__global__ __launch_bounds__(256)
void cvt_kernel(CvtArgs a, const unsigned short* __restrict__ x0,
                int* __restrict__ flagp)
{
  __shared__ int sbad;
  if (threadIdx.x == 0) sbad = 0;
  __syncthreads();
  {
    float v = bf2f(x0[threadIdx.x]);
    if (!(fabsf(v) <= 1e6f)) sbad = 1;   // benign race, same value
  }
  __syncthreads();
  const int isf32 = sbad;
  if (blockIdx.x == 0 && threadIdx.x == 0) *flagp = isf32;

  int c = blockIdx.x;
  int ti = 0;
  while (c >= a.ccum[ti + 1]) ti++;
  int j = (c - a.ccum[ti]) * 2048 + threadIdx.x * 8;
  if (j >= a.nel[ti]) return;
  if (isf32) {
    const float* s = (const float*)a.src[ti];
    f32x4 v0 = *(const f32x4*)(s + j);
    f32x4 v1 = *(const f32x4*)(s + j + 4);
    u16x8 o;
    #pragma unroll
    for (int k = 0; k < 4; k++) { o[k] = f2bbits(v0[k]); o[k + 4] = f2bbits(v1[k]); }
    *(u16x8*)((u16*)a.dst[ti] + j) = o;
  } else {
    *(u16x8*)((u16*)a.dst[ti] + j) = *(const u16x8*)((const u16*)a.src[ti] + j);
  }
}

// ---------------------------------------------------------------------------
// GEMM 128x128, BK=64, XOR-swizzled LDS, double-buffered, counted vmcnt.
// Now only used for the in_proj 160-column tail (N=160, ldout=4256).
// EPI 0: store bf16   EPI 2: store bf16(gelu(acc+bias))
// ---------------------------------------------------------------------------
template<int EPI>
__global__ __launch_bounds__(256, 2)
void gemm_bt(const bf16* __restrict__ A, const bf16* __restrict__ W,
             int M, int N, int K, int ldout,
             bf16* __restrict__ outB,
             const bf16* __restrict__ bias)
{
  __shared__ __align__(16) bhalf sA[2][128 * 64];
  __shared__ __align__(16) bhalf sW[2][128 * 64];
  const int nbx   = gridDim.x;
  const int total = nbx * gridDim.y;
  const int lin   = blockIdx.y * nbx + blockIdx.x;
  const int chunk = total >> 3;
  const int swz   = ((total & 7) == 0) ? ((lin & 7) * chunk + (lin >> 3)) : lin;
  const int n0   = (swz % nbx) * 128;
  const int m0   = (swz / nbx) * 128;
  const int t    = threadIdx.x;
  const int w    = t >> 6;
  const int lane = t & 63;
  const int wm   = (w >> 1) * 64;
  const int wn   = (w & 1) * 64;
  const int lr   = lane & 15;
  const int lq   = lane >> 4;

  f32x4 acc[4][4];
  #pragma unroll
  for (int i = 0; i < 4; i++)
    #pragma unroll
    for (int j = 0; j < 4; j++)
      acc[i][j] = (f32x4){0.f, 0.f, 0.f, 0.f};

  auto stage = [&](int buf, int kk0) {
    #pragma unroll
    for (int j = 0; j < 4; j++) {
      int s  = t + 256 * j;
      int r  = s >> 3;
      int cs = (s & 7) ^ (r & 7);
      load_lds16(A + (size_t)(m0 + r) * K + kk0 + cs * 8, &sA[buf][s * 8]);
      int wr = n0 + r; wr = wr < N ? wr : N - 1;
      load_lds16(W + (size_t)wr * K + kk0 + cs * 8, &sW[buf][s * 8]);
    }
  };

  stage(0, 0);                          // 8 loads in flight

  int cur = 0;
  for (int k0 = 0; k0 < K; k0 += 64) {
    const bool more = (k0 + 64 < K);
    if (more) stage(cur ^ 1, k0 + 64);  // +8 loads; do NOT wait on these now
    if (more) asm volatile("s_waitcnt vmcnt(8)" ::: "memory");
    else      asm volatile("s_waitcnt vmcnt(0)" ::: "memory");
    __builtin_amdgcn_s_barrier();       // all waves: buffer `cur` fully landed
    asm volatile("" ::: "memory");

    const bhalf* pA = sA[cur];
    const bhalf* pW = sW[cur];
    #pragma unroll
    for (int kk = 0; kk < 2; kk++) {
      bhalf8 af[4], bfr[4];
      #pragma unroll
      for (int i = 0; i < 4; i++) {
        int r = wm + i * 16 + lr;
        int c = (kk * 4 + lq) ^ (r & 7);
        af[i] = *(const bhalf8*)(pA + r * 64 + c * 8);
      }
      #pragma unroll
      for (int j = 0; j < 4; j++) {
        int r = wn + j * 16 + lr;
        int c = (kk * 4 + lq) ^ (r & 7);
        bfr[j] = *(const bhalf8*)(pW + r * 64 + c * 8);
      }
      #pragma unroll
      for (int i = 0; i < 4; i++)
        #pragma unroll
        for (int j = 0; j < 4; j++)
          acc[i][j] = __builtin_amdgcn_mfma_f32_16x16x32_bf16(af[i], bfr[j], acc[i][j], 0, 0, 0);
    }
    __builtin_amdgcn_s_barrier();       // all waves' ds_reads of `cur` retired
    asm volatile("" ::: "memory");
    cur ^= 1;
  }

  #pragma unroll
  for (int i = 0; i < 4; i++) {
    #pragma unroll
    for (int j = 0; j < 4; j++) {
      #pragma unroll
      for (int r = 0; r < 4; r++) {
        int m = m0 + wm + i * 16 + lq * 4 + r;
        int n = n0 + wn + j * 16 + lr;
        if (n < N) {
          float v = acc[i][j][r];
          size_t idx = (size_t)m * ldout + n;
          if (EPI == 0) {
            outB[idx] = __float2bfloat16(v);
          } else {
            v += __bfloat162float(bias[n]);
            outB[idx] = __float2bfloat16(0.5f * v * (1.0f + erff(v * 0.70710678118654752f)));
          }
        }
      }
    }
  }
}

// ---------------------------------------------------------------------------
// GEMM 256x256, BK=64, 512 threads (8 waves, 2m x 4n), XOR-swizzled LDS,
// double-buffered, counted vmcnt(8) (full-tile prefetch cover), now with a
// 4-phase barrier-delimited compute schedule (T3-style) + s_setprio around
// each MFMA cluster (T5; pays only given phase role-split per catalog).
// Phase p = (kk, ihalf): {ds_read frags -> setprio(1) -> 16 MFMA ->
// setprio(0) -> s_barrier}. Staging stays all-at-phase-0: our consumption
// order needs every quarter of the tile at phase 0 (each wave reads its own
// fixed A/B slice each phase), so per-phase stage interleave would give the
// last-staged part only 1 phase of flight; all-at-once gives uniform
// full-tile cover with vmcnt(8).
// Requires M%256==0, N%256==0. ldout decouples output stride (in_proj writes
// into a 4256-wide buffer). LDS 128 KiB -> 1 block/CU.
// ---------------------------------------------------------------------------
template<int EPI>
__global__ __launch_bounds__(512, 2)
void gemm256_bt(const bf16* __restrict__ A, const bf16* __restrict__ W,
                int M, int N, int K, int ldout,
                bf16* __restrict__ outB,
                const bf16* __restrict__ bias)
{
  __shared__ __align__(16) bhalf sA[2][256 * 64];
  __shared__ __align__(16) bhalf sW[2][256 * 64];
  const int nbx   = gridDim.x;
  const int total = nbx * gridDim.y;
  const int lin   = blockIdx.y * nbx + blockIdx.x;
  const int chunk = total >> 3;
  const int swz   = ((total & 7) == 0) ? ((lin & 7) * chunk + (lin >> 3)) : lin;
  const int n0   = (swz % nbx) * 256;
  const int m0   = (swz / nbx) * 256;
  const int t    = threadIdx.x;
  const int w    = t >> 6;
  const int lane = t & 63;
  const int wm   = (w >> 2) * 128;     // 2 wave-rows of 128
  const int wn   = (w & 3) * 64;       // 4 wave-cols of 64
  const int lr   = lane & 15;
  const int lq   = lane >> 4;

  f32x4 acc[8][4];
  #pragma unroll
  for (int i = 0; i < 8; i++)
    #pragma unroll
    for (int j = 0; j < 4; j++)
      acc[i][j] = (f32x4){0.f, 0.f, 0.f, 0.f};

  auto stage = [&](int buf, int kk0) {
    #pragma unroll
    for (int j = 0; j < 4; j++) {
      int s  = t + 512 * j;            // 0..2047 : 256 rows x 8 chunks
      int r  = s >> 3;
      int cs = (s & 7) ^ (r & 7);
      load_lds16(A + (size_t)(m0 + r) * K + kk0 + cs * 8, &sA[buf][s * 8]);
    }
    #pragma unroll
    for (int j = 0; j < 4; j++) {
      int s  = t + 512 * j;
      int r  = s >> 3;
      int cs = (s & 7) ^ (r & 7);
      load_lds16(W + (size_t)(n0 + r) * K + kk0 + cs * 8, &sW[buf][s * 8]);
    }
  };

  stage(0, 0);                          // 8 loads in flight

  int cur = 0;
  for (int k0 = 0; k0 < K; k0 += 64) {
    const bool more = (k0 + 64 < K);
    if (more) stage(cur ^ 1, k0 + 64);  // +8 loads; keep them flying all tile
    if (more) asm volatile("s_waitcnt vmcnt(8)" ::: "memory");
    else      asm volatile("s_waitcnt vmcnt(0)" ::: "memory");
    __builtin_amdgcn_s_barrier();       // buffer `cur` fully landed, all waves
    asm volatile("" ::: "memory");

    const bhalf* pA = sA[cur];
    const bhalf* pW = sW[cur];
    bhalf8 af[4], bfr[4];

    // ---- phase 0: kk=0, i-half=0 ----
    #pragma unroll
    for (int j = 0; j < 4; j++) {
      int r = wn + j * 16 + lr;
      int c = lq ^ (r & 7);
      bfr[j] = *(const bhalf8*)(pW + r * 64 + c * 8);
    }
    #pragma unroll
    for (int i = 0; i < 4; i++) {
      int r = wm + i * 16 + lr;
      int c = lq ^ (r & 7);
      af[i] = *(const bhalf8*)(pA + r * 64 + c * 8);
    }
    __builtin_amdgcn_s_setprio(1);
    #pragma unroll
    for (int i = 0; i < 4; i++)
      #pragma unroll
      for (int j = 0; j < 4; j++)
        acc[i][j] = __builtin_amdgcn_mfma_f32_16x16x32_bf16(af[i], bfr[j], acc[i][j], 0, 0, 0);
    __builtin_amdgcn_s_setprio(0);
    __builtin_amdgcn_s_barrier();
    asm volatile("" ::: "memory");

    // ---- phase 1: kk=0, i-half=1 (bfr reused from phase 0) ----
    #pragma unroll
    for (int i = 0; i < 4; i++) {
      int r = wm + 64 + i * 16 + lr;
      int c = lq ^ (r & 7);
      af[i] = *(const bhalf8*)(pA + r * 64 + c * 8);
    }
    __builtin_amdgcn_s_setprio(1);
    #pragma unroll
    for (int i = 0; i < 4; i++)
      #pragma unroll
      for (int j = 0; j < 4; j++)
        acc[4 + i][j] = __builtin_amdgcn_mfma_f32_16x16x32_bf16(af[i], bfr[j], acc[4 + i][j], 0, 0, 0);
    __builtin_amdgcn_s_setprio(0);
    __builtin_amdgcn_s_barrier();
    asm volatile("" ::: "memory");

    // ---- phase 2: kk=1, i-half=0 ----
    #pragma unroll
    for (int j = 0; j < 4; j++) {
      int r = wn + j * 16 + lr;
      int c = (4 + lq) ^ (r & 7);
      bfr[j] = *(const bhalf8*)(pW + r * 64 + c * 8);
    }
    #pragma unroll
    for (int i = 0; i < 4; i++) {
      int r = wm + i * 16 + lr;
      int c = (4 + lq) ^ (r & 7);
      af[i] = *(const bhalf8*)(pA + r * 64 + c * 8);
    }
    __builtin_amdgcn_s_setprio(1);
    #pragma unroll
    for (int i = 0; i < 4; i++)
      #pragma unroll
      for (int j = 0; j < 4; j++)
        acc[i][j] = __builtin_amdgcn_mfma_f32_16x16x32_bf16(af[i], bfr[j], acc[i][j], 0, 0, 0);
    __builtin_amdgcn_s_setprio(0);
    __builtin_amdgcn_s_barrier();
    asm volatile("" ::: "memory");

    // ---- phase 3: kk=1, i-half=1 ----
    #pragma unroll
    for (int i = 0; i < 4; i++) {
      int r = wm + 64 + i * 16 + lr;
      int c = (4 + lq) ^ (r & 7);
      af[i] = *(const bhalf8*)(pA + r * 64 + c * 8);
    }
    __builtin_amdgcn_s_setprio(1);
    #pragma unroll
    for (int i = 0; i < 4; i++)
      #pragma unroll
      for (int j = 0; j < 4; j++)
        acc[4 + i][j] = __builtin_amdgcn_mfma_f32_16x16x32_bf16(af[i], bfr[j], acc[4 + i][j], 0, 0, 0);
    __builtin_amdgcn_s_setprio(0);
    __builtin_amdgcn_s_barrier();       // all reads of `cur` retired
    asm volatile("" ::: "memory");

    cur ^= 1;
  }

  #pragma unroll
  for (int i = 0; i < 8; i++) {
    #pragma unroll
    for (int j = 0; j < 4; j++) {
      #pragma unroll
      for (int r = 0; r < 4; r++) {
        int m = m0 + wm + i * 16 + lq * 4 + r;
        int n = n0 + wn + j * 16 + lr;
        float v = acc[i][j][r];
        size_t idx = (size_t)m * ldout + n;
        if (EPI == 0) {
          outB[idx] = __float2bfloat16(v);
        } else {
          v += __bfloat162float(bias[n]);
          outB[idx] = __float2bfloat16(0.5f * v * (1.0f + erff(v * 0.70710678118654752f)));
        }
      }
    }
  }
}

// ---------------------------------------------------------------------------
// Skinny GEMM 64x128 tile, split-K=SK (N=1024): grid = 512*SK blocks,
// fp32 partials; epilogues live in the reduce kernels.
// ---------------------------------------------------------------------------
struct SkParts4 { float* p[4]; };

template<int SK>
__global__ __launch_bounds__(256, 4)
void gemm_skinny_sk(const bf16* __restrict__ A, const bf16* __restrict__ W,
                    int M, int N, int K, SkParts4 parts)
{
  __shared__ __align__(16) bhalf sA[64 * 64];
  __shared__ __align__(16) bhalf sW[128 * 64];
  const int id   = blockIdx.x;
  const int z    = id >> 9;            // split index (grid = 512*SK)
  const int id9  = id & 511;
  const int hi   = id9 >> 6;
  const int rem  = id9 & 63;
  const int jn   = rem >> 3;
  const int mi   = hi * 8 + (rem & 7);
  const int m0   = mi * 64;
  const int n0   = jn * 128;
  const int t    = threadIdx.x;
  const int w    = t >> 6;
  const int lane = t & 63;
  const int wm   = (w >> 1) * 32;
  const int wn   = (w & 1) * 64;
  const int lr   = lane & 15;
  const int lq   = lane >> 4;

  f32x4 acc[2][4];
  #pragma unroll
  for (int i = 0; i < 2; i++)
    #pragma unroll
    for (int j = 0; j < 4; j++)
      acc[i][j] = (f32x4){0.f, 0.f, 0.f, 0.f};

  const int kh = K / SK;
  const int kend = z * kh + kh;
  for (int k0 = z * kh; k0 < kend; k0 += 64) {
    #pragma unroll
    for (int j = 0; j < 2; j++) {
      int s  = t + 256 * j;
      int r  = s >> 3;
      int cs = (s & 7) ^ (r & 7);
      load_lds16(A + (size_t)(m0 + r) * K + k0 + cs * 8, sA + s * 8);
    }
    #pragma unroll
    for (int j = 0; j < 4; j++) {
      int s  = t + 256 * j;
      int r  = s >> 3;
      int cs = (s & 7) ^ (r & 7);
      load_lds16(W + (size_t)(n0 + r) * K + k0 + cs * 8, sW + s * 8);
    }
    __syncthreads();
    #pragma unroll
    for (int kk = 0; kk < 2; kk++) {
      bhalf8 af[2], bfr[4];
      #pragma unroll
      for (int i = 0; i < 2; i++) {
        int r = wm + i * 16 + lr;
        int c = (kk * 4 + lq) ^ (r & 7);
        af[i] = *(const bhalf8*)(sA + r * 64 + c * 8);
      }
      #pragma unroll
      for (int j = 0; j < 4; j++) {
        int r = wn + j * 16 + lr;
        int c = (kk * 4 + lq) ^ (r & 7);
        bfr[j] = *(const bhalf8*)(sW + r * 64 + c * 8);
      }
      #pragma unroll
      for (int i = 0; i < 2; i++)
        #pragma unroll
        for (int j = 0; j < 4; j++)
          acc[i][j] = __builtin_amdgcn_mfma_f32_16x16x32_bf16(af[i], bfr[j], acc[i][j], 0, 0, 0);
    }
    __syncthreads();
  }

  float* out = parts.p[z];
  #pragma unroll
  for (int i = 0; i < 2; i++)
    #pragma unroll
    for (int j = 0; j < 4; j++)
      #pragma unroll
      for (int r = 0; r < 4; r++) {
        int m = m0 + wm + i * 16 + lq * 4 + r;
        int n = n0 + wn + j * 16 + lr;
        out[(size_t)m * N + n] = acc[i][j][r];
      }
}

// ---------------------------------------------------------------------------
// out_proj reduce + residual + FULL ln2, one block per row:
//   x2f = p0 + p1 + resB;  hln = LN(x2f)*w+b (bf16)
// ---------------------------------------------------------------------------
__global__ __launch_bounds__(256)
void reduce_out_ln2_kernel(const float* __restrict__ p0, const float* __restrict__ p1,
                           const bf16* __restrict__ resB, float* __restrict__ x2f,
                           const bf16* __restrict__ w, const bf16* __restrict__ b,
                           bf16* __restrict__ hln)
{
  int row = blockIdx.x, t = threadIdx.x;
  int i = row * 256 + t;
  __shared__ float rs[4], rq[4];
  f32x4 a = ((const f32x4*)p0)[i];
  f32x4 bb = ((const f32x4*)p1)[i];
  u16x4 r = ((const u16x4*)resB)[i];
  f32x4 o;
  float s = 0.f, ss = 0.f;
  #pragma unroll
  for (int j = 0; j < 4; j++) {
    o[j] = a[j] + bb[j] + bf2f(r[j]);
    s += o[j]; ss += o[j] * o[j];
  }
  ((f32x4*)x2f)[i] = o;
  #pragma unroll
  for (int off = 32; off; off >>= 1) { s += __shfl_down(s, off); ss += __shfl_down(ss, off); }
  if ((t & 63) == 0) { rs[t >> 6] = s; rq[t >> 6] = ss; }
  __syncthreads();
  float S = rs[0] + rs[1] + rs[2] + rs[3];
  float Q = rq[0] + rq[1] + rq[2] + rq[3];
  float mean = S * (1.f / D_MODEL);
  float rstd = rsqrtf(Q * (1.f / D_MODEL) - mean * mean + 1e-5f);
  u16x4 wv = ((const u16x4*)w)[t];
  u16x4 bv = ((const u16x4*)b)[t];
  u16x4 ov;
  #pragma unroll
  for (int j = 0; j < 4; j++)
    ov[j] = f2bbits((o[j] - mean) * rstd * bf2f(wv[j]) + bf2f(bv[j]));
  ((u16x4*)hln)[i] = ov;
}

// ---------------------------------------------------------------------------
// ffn2 reduce: d_out = p0+p1+p2+p3 + bias + resF (dtype per flag)
// ---------------------------------------------------------------------------
__global__ __launch_bounds__(256)
void reduce_ffn_kernel(const float* __restrict__ p0, const float* __restrict__ p1,
                       const float* __restrict__ p2, const float* __restrict__ p3,
                       const bf16* __restrict__ bias, const float* __restrict__ resF,
                       void* __restrict__ outp, const int* __restrict__ flagp)
{
  int i = blockIdx.x * 256 + threadIdx.x;
  int n4 = i & (D_MODEL / 4 - 1);
  f32x4 v0 = ((const f32x4*)p0)[i];
  f32x4 v1 = ((const f32x4*)p1)[i];
  f32x4 v2 = ((const f32x4*)p2)[i];
  f32x4 v3 = ((const f32x4*)p3)[i];
  f32x4 rf = ((const f32x4*)resF)[i];
  u16x4 bb = ((const u16x4*)bias)[n4];
  f32x4 o;
  #pragma unroll
  for (int j = 0; j < 4; j++)
    o[j] = ((v0[j] + v1[j]) + (v2[j] + v3[j])) + rf[j] + bf2f(bb[j]);
  if (*flagp) {
    ((f32x4*)outp)[i] = o;
  } else {
    u16x4 ov;
    #pragma unroll
    for (int j = 0; j < 4; j++) ov[j] = f2bbits(o[j]);
    ((u16x4*)outp)[i] = ov;
  }
}

// ---------------------------------------------------------------------------
// Fused ln0 + ln1; reads x directly from d_in (fp32/bf16 per flag); float4.
// ---------------------------------------------------------------------------
__global__ __launch_bounds__(256)
void ln01_kernel(const void* __restrict__ xin, const int* __restrict__ flagp,
                 const bf16* __restrict__ w0, const bf16* __restrict__ b0,
                 const bf16* __restrict__ w1, const bf16* __restrict__ b1,
                 bf16* __restrict__ x0o, bf16* __restrict__ x1o)
{
  int row = blockIdx.x, t = threadIdx.x;
  int i = row * 256 + t;
  __shared__ float rs[4], rq[4];
  float v[4], s = 0.f, ss = 0.f;
  if (*flagp) {
    f32x4 xv = ((const f32x4*)xin)[i];
    #pragma unroll
    for (int j = 0; j < 4; j++) v[j] = xv[j];
  } else {
    u16x4 xv = ((const u16x4*)xin)[i];
    #pragma unroll
    for (int j = 0; j < 4; j++) v[j] = bf2f(xv[j]);
  }
  #pragma unroll
  for (int j = 0; j < 4; j++) { s += v[j]; ss += v[j] * v[j]; }
  #pragma unroll
  for (int o = 32; o; o >>= 1) { s += __shfl_down(s, o); ss += __shfl_down(ss, o); }
  if ((t & 63) == 0) { rs[t >> 6] = s; rq[t >> 6] = ss; }
  __syncthreads();
  float S = rs[0] + rs[1] + rs[2] + rs[3];
  float Q = rq[0] + rq[1] + rq[2] + rq[3];
  float mean = S * (1.f / D_MODEL);
  float rstd = rsqrtf(Q * (1.f / D_MODEL) - mean * mean + 1e-5f);
  u16x4 w0v = ((const u16x4*)w0)[t], b0v = ((const u16x4*)b0)[t];
  float u[4]; s = 0.f; ss = 0.f;
  u16x4 o0;
  #pragma unroll
  for (int j = 0; j < 4; j++) {
    u[j] = (v[j] - mean) * rstd * bf2f(w0v[j]) + bf2f(b0v[j]);
    s += u[j]; ss += u[j] * u[j];
    o0[j] = f2bbits(u[j]);
  }
  ((u16x4*)x0o)[i] = o0;
  __syncthreads();
  #pragma unroll
  for (int o = 32; o; o >>= 1) { s += __shfl_down(s, o); ss += __shfl_down(ss, o); }
  if ((t & 63) == 0) { rs[t >> 6] = s; rq[t >> 6] = ss; }
  __syncthreads();
  S = rs[0] + rs[1] + rs[2] + rs[3];
  Q = rq[0] + rq[1] + rq[2] + rq[3];
  mean = S * (1.f / D_MODEL);
  rstd = rsqrtf(Q * (1.f / D_MODEL) - mean * mean + 1e-5f);
  u16x4 w1v = ((const u16x4*)w1)[t], b1v = ((const u16x4*)b1)[t];
  u16x4 o1;
  #pragma unroll
  for (int j = 0; j < 4; j++)
    o1[j] = f2bbits((u[j] - mean) * rstd * bf2f(w1v[j]) + bf2f(b1v[j]));
  ((u16x4*)x1o)[i] = o1;
}

// ---------------------------------------------------------------------------
// Causal depthwise conv (k=4) + SiLU -> bf16 xact, vectorized 8 ch/thread.
// Grid dim3(2, NROWS); block.x=1 tail threads compute dt/lda.
// ---------------------------------------------------------------------------
__device__ __forceinline__ void conv8(const bf16* __restrict__ zxb,
                                      const bf16* __restrict__ cw,
                                      const bf16* __restrict__ cb,
                                      bf16* __restrict__ xact, int row, int c0)
{
  int l = row & (SEQ - 1);
  float acc[8];
  {
    bhalf8 cbv = *(const bhalf8*)(cb + c0);
    #pragma unroll
    for (int j = 0; j < 8; j++) acc[j] = (float)cbv[j];
  }
  bhalf wts[32];
  #pragma unroll
  for (int q = 0; q < 4; q++)
    *(bhalf8*)(wts + q * 8) = *(const bhalf8*)(cw + c0 * 4 + q * 8);
  #pragma unroll
  for (int k = 0; k < 4; k++) {
    int lt = l - 3 + k;
    if (lt >= 0) {
      bhalf8 xv = *(const bhalf8*)(zxb + (size_t)(row - 3 + k) * D_IN_PROJ + D_INNER + c0);
      #pragma unroll
      for (int j = 0; j < 8; j++)
        acc[j] = fmaf((float)xv[j], (float)wts[j * 4 + k], acc[j]);
    }
  }
  bhalf8 o;
  #pragma unroll
  for (int j = 0; j < 8; j++) {
    float a = acc[j];
    o[j] = (bhalf)(a / (1.f + expf(-a)));
  }
  *(bhalf8*)(xact + (size_t)row * CONV_DIM + c0) = o;
}

__global__ __launch_bounds__(256)
void conv_silu_dt_kernel(const bf16* __restrict__ zxb, const bf16* __restrict__ cw,
                         const bf16* __restrict__ cb, bf16* __restrict__ xact,
                         const bf16* __restrict__ dtb, const bf16* __restrict__ alog,
                         float* __restrict__ dts, float* __restrict__ ldab)
{
  const int row = blockIdx.y;
  const int t = threadIdx.x;
  if (blockIdx.x == 0) {
    conv8(zxb, cw, cb, xact, row, t * 8);
  } else {
    if (t < 16) {
      conv8(zxb, cw, cb, xact, row, 2048 + t * 8);
    } else if (t < 48) {
      int h = t - 16;
      float v = __bfloat162float(zxb[(size_t)row * D_IN_PROJ + (D_INNER + CONV_DIM) + h]) +
                __bfloat162float(dtb[h]);
      float sp = (v > 20.f) ? v : log1pf(expf(v));
      dts[row * NHEADS + h] = sp;
      ldab[row * NHEADS + h] = -sp * expf(__bfloat162float(alog[h]));
    }
  }
}

// ---------------------------------------------------------------------------
// MFMA chunk scan, pass 1 (chunk states).
// ---------------------------------------------------------------------------
__global__ __launch_bounds__(256)
void scan_state_kernel(const bf16* __restrict__ xact, const float* __restrict__ dts,
                       const float* __restrict__ ldab, bf16* __restrict__ Sbuf,
                       float* __restrict__ acb)
{
  __shared__ __align__(16) bf16 wBT[64][72];
  __shared__ __align__(16) bf16 XT[64][72];
  __shared__ float lsS[64], dtS[64];
  const int bid = blockIdx.x;
  const int bh = bid & 63, c = bid >> 6;
  const int b = bh >> 5, h = bh & 31;
  const int t0 = c * TC;
  const int tid = threadIdx.x;
  const int w = tid >> 6, lane = tid & 63;
  const int lr = lane & 15, lq = lane >> 4;

  if (w == 0) {
    float v = ldab[(size_t)(b * SEQ + t0 + lane) * NHEADS + h];
    #pragma unroll
    for (int o = 1; o < 64; o <<= 1) {
      float up = __shfl_up(v, o);
      if (lane >= o) v += up;
    }
    lsS[lane] = v;
    dtS[lane] = dts[(size_t)(b * SEQ + t0 + lane) * NHEADS + h];
  }
  __syncthreads();
  const float lsT = lsS[63];
  {
    int nn = tid & 63, u0 = (tid >> 6) * 16;
    for (int i = 0; i < 16; i++) {
      int u = u0 + i;
      const bf16* rowp = xact + (size_t)(b * SEQ + t0 + u) * CONV_DIM;
      float wgt = dtS[u] * __expf(lsT - lsS[u]);
      wBT[nn][u] = __float2bfloat16(__bfloat162float(rowp[D_INNER + nn]) * wgt);
      XT[nn][u]  = rowp[h * 64 + nn];
    }
  }
  __syncthreads();

  bhalf8 af0 = *(const bhalf8*)&wBT[16 * w + lr][lq * 8];
  bhalf8 af1 = *(const bhalf8*)&wBT[16 * w + lr][32 + lq * 8];
  bf16* sb = Sbuf + ((size_t)bh * NCH + c) * 4096;
  #pragma unroll
  for (int jt = 0; jt < 4; jt++) {
    bhalf8 xf0 = *(const bhalf8*)&XT[16 * jt + lr][lq * 8];
    bhalf8 xf1 = *(const bhalf8*)&XT[16 * jt + lr][32 + lq * 8];
    f32x4 acc = (f32x4){0.f, 0.f, 0.f, 0.f};
    acc = __builtin_amdgcn_mfma_f32_16x16x32_bf16(af0, xf0, acc, 0, 0, 0);
    acc = __builtin_amdgcn_mfma_f32_16x16x32_bf16(af1, xf1, acc, 0, 0, 0);
    #pragma unroll
    for (int r = 0; r < 4; r++) {
      int n = 16 * w + lq * 4 + r;
      int p = 16 * jt + lr;
      sb[p * 64 + n] = __float2bfloat16(acc[r]);
    }
  }
  if (tid == 0) acb[bh * NCH + c] = __expf(lsT);
}

// ---------------------------------------------------------------------------
// Pass 2: serial inter-chunk propagation (in-place).
// ---------------------------------------------------------------------------
__global__ __launch_bounds__(256)
void state_prop_kernel(bf16* __restrict__ Sbuf, const float* __restrict__ acb)
{
  const int bh = blockIdx.x >> 2, q = blockIdx.x & 3;
  const int t = threadIdx.x;
  bf16* sp = Sbuf + (size_t)bh * NCH * 4096 + q * 1024 + t;
  const float* ap = acb + bh * NCH;
  float h0 = 0.f, h1 = 0.f, h2 = 0.f, h3 = 0.f;
  for (int c = 0; c < NCH; c++) {
    bf16* pc = sp + (size_t)c * 4096;
    float s0 = __bfloat162float(pc[0]);
    float s1 = __bfloat162float(pc[256]);
    float s2 = __bfloat162float(pc[512]);
    float s3 = __bfloat162float(pc[768]);
    float a = ap[c];
    pc[0]   = __float2bfloat16(h0);
    pc[256] = __float2bfloat16(h1);
    pc[512] = __float2bfloat16(h2);
    pc[768] = __float2bfloat16(h3);
    h0 = fmaf(h0, a, s0); h1 = fmaf(h1, a, s1);
    h2 = fmaf(h2, a, s2); h3 = fmaf(h3, a, s3);
  }
}

// ---------------------------------------------------------------------------
// MFMA chunk scan, pass 3.
// ---------------------------------------------------------------------------
__global__ __launch_bounds__(256)
void scan_y_kernel(const bf16* __restrict__ xact, const float* __restrict__ dts,
                   const float* __restrict__ ldab, const bf16* __restrict__ Sbuf,
                   bf16* __restrict__ yfull)
{
  __shared__ __align__(16) bf16 Cs[64][72];
  __shared__ __align__(16) bf16 Bs[64][72];    // reused for M after G loop
  __shared__ __align__(16) bf16 XT[64][72];
  __shared__ __align__(16) bf16 HT[64][72];
  __shared__ float lsS[64], dtS[64];
  const int bid = blockIdx.x;
  const int bh = bid & 63, c = bid >> 6;
  const int b = bh >> 5, h = bh & 31;
  const int t0 = c * TC;
  const int tid = threadIdx.x;
  const int w = tid >> 6, lane = tid & 63;
  const int lr = lane & 15, lq = lane >> 4;

  if (w == 0) {
    float v = ldab[(size_t)(b * SEQ + t0 + lane) * NHEADS + h];
    #pragma unroll
    for (int o = 1; o < 64; o <<= 1) {
      float up = __shfl_up(v, o);
      if (lane >= o) v += up;
    }
    lsS[lane] = v;
    dtS[lane] = dts[(size_t)(b * SEQ + t0 + lane) * NHEADS + h];
  }
  {
    int nn = tid & 63, u0 = (tid >> 6) * 16;
    for (int i = 0; i < 16; i++) {
      int u = u0 + i;
      const bf16* rowp = xact + (size_t)(b * SEQ + t0 + u) * CONV_DIM;
      Bs[u][nn] = rowp[D_INNER + nn];
      Cs[u][nn] = rowp[D_INNER + 64 + nn];
      XT[nn][u] = rowp[h * 64 + nn];
    }
    const bf16* sb = Sbuf + ((size_t)bh * NCH + c) * 4096;
    for (int i = 0; i < 16; i++) {
      int e = tid + 256 * i;
      HT[e >> 6][e & 63] = sb[e];
    }
  }
  __syncthreads();

  bhalf8 cf0 = *(const bhalf8*)&Cs[16 * w + lr][lq * 8];
  bhalf8 cf1 = *(const bhalf8*)&Cs[16 * w + lr][32 + lq * 8];
  f32x4 accH[4];
  float mreg[4][4];
  #pragma unroll
  for (int jt = 0; jt < 4; jt++) {
    bhalf8 bf0 = *(const bhalf8*)&Bs[16 * jt + lr][lq * 8];
    bhalf8 bf1 = *(const bhalf8*)&Bs[16 * jt + lr][32 + lq * 8];
    f32x4 g = (f32x4){0.f, 0.f, 0.f, 0.f};
    g = __builtin_amdgcn_mfma_f32_16x16x32_bf16(cf0, bf0, g, 0, 0, 0);
    g = __builtin_amdgcn_mfma_f32_16x16x32_bf16(cf1, bf1, g, 0, 0, 0);
    bhalf8 hf0 = *(const bhalf8*)&HT[16 * jt + lr][lq * 8];
    bhalf8 hf1 = *(const bhalf8*)&HT[16 * jt + lr][32 + lq * 8];
    f32x4 ah = (f32x4){0.f, 0.f, 0.f, 0.f};
    ah = __builtin_amdgcn_mfma_f32_16x16x32_bf16(cf0, hf0, ah, 0, 0, 0);
    ah = __builtin_amdgcn_mfma_f32_16x16x32_bf16(cf1, hf1, ah, 0, 0, 0);
    accH[jt] = ah;
    #pragma unroll
    for (int r = 0; r < 4; r++) {
      int t = 16 * w + lq * 4 + r;
      int u = 16 * jt + lr;
      float m = 0.f;
      if (u <= t) m = g[r] * __expf(lsS[t] - lsS[u]) * dtS[u];
      mreg[jt][r] = m;
    }
  }
  __syncthreads();               // all Bs reads complete
  #pragma unroll
  for (int jt = 0; jt < 4; jt++)
    #pragma unroll
    for (int r = 0; r < 4; r++)
      Bs[16 * w + lq * 4 + r][16 * jt + lr] = __float2bfloat16(mreg[jt][r]);
  __syncthreads();

  bhalf8 mf0 = *(const bhalf8*)&Bs[16 * w + lr][lq * 8];
  bhalf8 mf1 = *(const bhalf8*)&Bs[16 * w + lr][32 + lq * 8];
  #pragma unroll
  for (int jt = 0; jt < 4; jt++) {
    bhalf8 xf0 = *(const bhalf8*)&XT[16 * jt + lr][lq * 8];
    bhalf8 xf1 = *(const bhalf8*)&XT[16 * jt + lr][32 + lq * 8];
    f32x4 acc = (f32x4){0.f, 0.f, 0.f, 0.f};
    acc = __builtin_amdgcn_mfma_f32_16x16x32_bf16(mf0, xf0, acc, 0, 0, 0);
    acc = __builtin_amdgcn_mfma_f32_16x16x32_bf16(mf1, xf1, acc, 0, 0, 0);
    #pragma unroll
    for (int r = 0; r < 4; r++) {
      int t = 16 * w + lq * 4 + r;
      int p = 16 * jt + lr;
      float y = acc[r] + __expf(lsS[t]) * accH[jt][r];
      yfull[(size_t)(b * SEQ + t0 + t) * D_INNER + h * 64 + p] = __float2bfloat16(y);
    }
  }
}

// ---------------------------------------------------------------------------
// y = yfull + D*x;  y *= silu(z);  RMSNorm * norm_w -> bf16.
// ---------------------------------------------------------------------------
__global__ __launch_bounds__(256)
void gate_rms_kernel(const bf16* __restrict__ yfull, const bf16* __restrict__ xact,
                     const bf16* __restrict__ zxb, const bf16* __restrict__ Dp,
                     const bf16* __restrict__ nw, bf16* __restrict__ yn)
{
  int row = blockIdx.x, t = threadIdx.x;
  int c0 = t * 8;
  __shared__ float rq[4];
  bhalf8 yv8 = *(const bhalf8*)(yfull + (size_t)row * D_INNER + c0);
  bhalf8 xv8 = *(const bhalf8*)(xact + (size_t)row * CONV_DIM + c0);
  bhalf8 zv8 = *(const bhalf8*)(zxb + (size_t)row * D_IN_PROJ + c0);
  float Dv = __bfloat162float(Dp[c0 >> 6]);
  float yv[8]; float ss = 0.f;
  #pragma unroll
  for (int j = 0; j < 8; j++) {
    float y = (float)yv8[j] + Dv * (float)xv8[j];
    float z = (float)zv8[j];
    yv[j] = y * (z / (1.f + expf(-z)));
    ss += yv[j] * yv[j];
  }
  #pragma unroll
  for (int o = 32; o; o >>= 1) ss += __shfl_down(ss, o);
  if ((t & 63) == 0) rq[t >> 6] = ss;
  __syncthreads();
  float tot = rq[0] + rq[1] + rq[2] + rq[3];
  float rr = rsqrtf(tot * (1.f / D_INNER) + 1e-5f);
  bhalf8 nv8 = *(const bhalf8*)(nw + c0);
  bhalf8 o;
  #pragma unroll
  for (int j = 0; j < 8; j++)
    o[j] = (bhalf)(yv[j] * rr * (float)nv8[j]);
  *(bhalf8*)(yn + (size_t)row * D_INNER + c0) = o;
}

// ---------------------------------------------------------------------------
extern "C" void kernel_launch(void* const* d_in, const int* in_sizes, int n_in,
                              void* d_out, int out_size, void* d_ws, size_t ws_size,
                              hipStream_t stream)
{
  char* ws = (char*)d_ws;
  bf16*  x1b   = (bf16*) (ws + 0);           //  [3->4]
  bf16*  Sbuf  = (bf16*) (ws + 0);           //  [7->9]   alias x1b (dead @4)
  bf16*  ynb   = (bf16*) (ws + 0);           //  [10->11] alias Sbuf
  float* pf0   = (float*)(ws + 0);           //  [14->14b] alias ynb
  bf16*  wproj = (bf16*) (ws + 16777216);    //  [2->4]
  float* acb   = (float*)(ws + 16777216);    //  [7->8]   alias wproj
  float* dtsb  = (float*)(ws + 16785408);    //  [5->9]   alias wproj
  float* ldab  = (float*)(ws + 17309696);    //  [5->9]   alias wproj
  float* pf1   = (float*)(ws + 16777216);    //  [14->14b] alias wproj region
  bf16*  wout  = (bf16*) (ws + 25493504);    //  [2->11]
  bf16*  w1c   = (bf16*) (ws + 29687808);    //  [2->13]
  bf16*  w2c   = (bf16*) (ws + 38076416);    //  [2->14]
  bf16*  ln0w  = (bf16*) (ws + 46465024);
  bf16*  ln0b  = (bf16*) (ws + 46467072);
  bf16*  ln1w  = (bf16*) (ws + 46469120);
  bf16*  ln1b  = (bf16*) (ws + 46471168);
  bf16*  ln2w  = (bf16*) (ws + 46473216);
  bf16*  ln2b  = (bf16*) (ws + 46475264);
  bf16*  convw = (bf16*) (ws + 46477312);
  bf16*  convb = (bf16*) (ws + 46494720);
  bf16*  dtb   = (bf16*) (ws + 46499072);
  bf16*  alog  = (bf16*) (ws + 46499136);
  bf16*  Dp    = (bf16*) (ws + 46499200);
  bf16*  normw = (bf16*) (ws + 46499264);
  bf16*  b1c   = (bf16*) (ws + 46503360);
  bf16*  b2c   = (bf16*) (ws + 46511552);
  int*   flag  = (int*)  (ws + 46513600);
  bf16*  x0b   = (bf16*) (ws + 46514176);    //  [3->11b]
  bf16*  zxb   = (bf16*) (ws + 54902784);    //  [4->10]
  float* x2f   = (float*)(ws + 54902784);    //  [11b->14b] alias zxb (ends 71.68M)
  float* pf3   = (float*)(ws + 71680000);    //  [14->14b] zxb tail (dead @10), ends 88.46M
  bf16*  xact  = (bf16*) (ws + 89767936);    //  [5->10]
  float* pout0 = (float*)(ws + 89767936);    //  [11->11b] alias xact
  float* pout1 = (float*)(ws + 106545152);   //  [11->11b]
  bf16*  gbuf  = (bf16*) (ws + 89767936);    //  [13->14] alias xact region
  bf16*  yfull = (bf16*) (ws + 125419520);   //  [9->10]
  bf16*  hln   = (bf16*) (ws + 125419520);   //  [11b->13] alias yfull
  float* pf2   = (float*)(ws + 125419520);   //  [14->14b] alias hln (dead @13)

  CvtArgs ca;
  void* dsts[NT] = { ln0w, ln0b, ln1w, ln1b, ln2w, ln2b, wproj, convw, convb,
                     dtb, alog, Dp, normw, wout, w1c, b1c, w2c, b2c };
  int cc = 0;
  ca.ccum[0] = 0;
  for (int i = 0; i < NT; i++) {
    ca.src[i] = d_in[i + 1];
    ca.dst[i] = dsts[i];
    ca.nel[i] = in_sizes[i + 1];
    cc += (in_sizes[i + 1] + 2047) / 2048;
    ca.ccum[i + 1] = cc;
  }
  cvt_kernel<<<cc, 256, 0, stream>>>(ca, (const unsigned short*)d_in[0], flag);

  ln01_kernel<<<NROWS, 256, 0, stream>>>(d_in[0], flag, ln0w, ln0b, ln1w, ln1b,
                                         x0b, x1b);

  // in_proj: 256^2 main (cols 0..4095, 256 blocks = 1/CU) + 128^2 tail
  // (cols 4096..4255, 64 blocks), both writing into zxb with ldout=4256.
  gemm256_bt<0><<<dim3(16, 16), 512, 0, stream>>>(x1b, wproj, NROWS, 4096, D_MODEL,
                                                  D_IN_PROJ, zxb, nullptr);
  gemm_bt<0><<<dim3(2, 32), 256, 0, stream>>>(x1b, wproj + (size_t)4096 * D_MODEL,
                                              NROWS, 160, D_MODEL, D_IN_PROJ,
                                              zxb + 4096, nullptr);

  conv_silu_dt_kernel<<<dim3(2, NROWS), 256, 0, stream>>>(zxb, convw, convb, xact,
                                                          dtb, alog, dtsb, ldab);

  scan_state_kernel<<<NCH * 64, 256, 0, stream>>>(xact, dtsb, ldab, Sbuf, acb);
  state_prop_kernel<<<64 * 4, 256, 0, stream>>>(Sbuf, acb);
  scan_y_kernel<<<NCH * 64, 256, 0, stream>>>(xact, dtsb, ldab, Sbuf, yfull);

  gate_rms_kernel<<<NROWS, 256, 0, stream>>>(yfull, xact, zxb, Dp, normw, ynb);

  // out_proj: 64x128 split-K=2 -> partials, then fused reduce+residual+ln2
  SkParts4 po = { { pout0, pout1, pout0, pout0 } };
  gemm_skinny_sk<2><<<1024, 256, 0, stream>>>(ynb, wout, NROWS, D_MODEL, D_INNER, po);
  reduce_out_ln2_kernel<<<NROWS, 256, 0, stream>>>(pout0, pout1, x0b, x2f,
                                                   ln2w, ln2b, hln);

  // ffn1: 256^2 4-phase counted-vmcnt pipeline (N=4096 exact, 256 blocks = 1/CU)
  gemm256_bt<2><<<dim3(16, 16), 512, 0, stream>>>(hln, w1c, NROWS, FFN_DIM, D_MODEL,
                                                  FFN_DIM, gbuf, b1c);

  // ffn2: 64x128 split-K=4 (2048 blocks, 8/CU) -> partials, then fused reduce
  SkParts4 pfp = { { pf0, pf1, pf2, pf3 } };
  gemm_skinny_sk<4><<<2048, 256, 0, stream>>>(gbuf, w2c, NROWS, D_MODEL, FFN_DIM, pfp);
  reduce_ffn_kernel<<<(NROWS * D_MODEL) / 1024, 256, 0, stream>>>(pf0, pf1, pf2, pf3,
                                                                  b2c, x2f, d_out, flag);
}

// Round 5
// 444.483 us; speedup vs baseline: 1.0215x; 1.0215x over previous
//
#include <hip/hip_runtime.h>
#include <hip/hip_bf16.h>
#include <math.h>

typedef __hip_bfloat16 bf16;
typedef __bf16 bhalf;
typedef bhalf bhalf8 __attribute__((ext_vector_type(8)));
typedef float f32x4 __attribute__((ext_vector_type(4)));
typedef unsigned short u16;
typedef u16 u16x4 __attribute__((ext_vector_type(4)));
typedef u16 u16x8 __attribute__((ext_vector_type(8)));

#define D_MODEL   1024
#define D_STATE   64
#define HEADDIM   64
#define D_INNER   2048
#define NHEADS    32
#define CONV_DIM  2176
#define D_IN_PROJ 4256
#define FFN_DIM   4096
#define BSZ       2
#define SEQ       2048
#define NROWS     (BSZ*SEQ)
#define TC        64
#define NCH       (SEQ/TC)

#define AS1 __attribute__((address_space(1)))
#define AS3 __attribute__((address_space(3)))
__device__ __forceinline__ void load_lds16(const void* g, void* l) {
  __builtin_amdgcn_global_load_lds((AS1 void*)g, (AS3 void*)l, 16, 0, 0);
}

__device__ __forceinline__ float bf2f(u16 u) {
  return __uint_as_float(((unsigned)u) << 16);
}
__device__ __forceinline__ u16 f2bbits(float f) {
  bf16 h = __float2bfloat16(f);
  return *(u16*)&h;
}

// ---------------------------------------------------------------------------
// Normalize weight inputs to bf16 copies; vectorized. Each block self-detects
// the input dtype. Block 0 publishes the flag for downstream consumers.
// ---------------------------------------------------------------------------
#define NT 18
struct CvtArgs {
  const void* src[NT];
  void*       dst[NT];
  int ccum[NT + 1];
  int nel[NT];
};

__global__ __launch_bounds__(256)
void cvt_kernel(CvtArgs a, const unsigned short* __restrict__ x0,
                int* __restrict__ flagp)
{
  __shared__ int sbad;
  if (threadIdx.x == 0) sbad = 0;
  __syncthreads();
  {
    float v = bf2f(x0[threadIdx.x]);
    if (!(fabsf(v) <= 1e6f)) sbad = 1;   // benign race, same value
  }
  __syncthreads();
  const int isf32 = sbad;
  if (blockIdx.x == 0 && threadIdx.x == 0) *flagp = isf32;

  int c = blockIdx.x;
  int ti = 0;
  while (c >= a.ccum[ti + 1]) ti++;
  int j = (c - a.ccum[ti]) * 2048 + threadIdx.x * 8;
  if (j >= a.nel[ti]) return;
  if (isf32) {
    const float* s = (const float*)a.src[ti];
    f32x4 v0 = *(const f32x4*)(s + j);
    f32x4 v1 = *(const f32x4*)(s + j + 4);
    u16x8 o;
    #pragma unroll
    for (int k = 0; k < 4; k++) { o[k] = f2bbits(v0[k]); o[k + 4] = f2bbits(v1[k]); }
    *(u16x8*)((u16*)a.dst[ti] + j) = o;
  } else {
    *(u16x8*)((u16*)a.dst[ti] + j) = *(const u16x8*)((const u16*)a.src[ti] + j);
  }
}

// ---------------------------------------------------------------------------
// GEMM 128x128, BK=64, XOR-swizzled LDS, double-buffered, counted vmcnt.
// Used for the in_proj 160-column tail (N=160, ldout=4256).
// EPI 0: store bf16   EPI 2: store bf16(gelu(acc+bias))
// ---------------------------------------------------------------------------
template<int EPI>
__global__ __launch_bounds__(256, 2)
void gemm_bt(const bf16* __restrict__ A, const bf16* __restrict__ W,
             int M, int N, int K, int ldout,
             bf16* __restrict__ outB,
             const bf16* __restrict__ bias)
{
  __shared__ __align__(16) bhalf sA[2][128 * 64];
  __shared__ __align__(16) bhalf sW[2][128 * 64];
  const int nbx   = gridDim.x;
  const int total = nbx * gridDim.y;
  const int lin   = blockIdx.y * nbx + blockIdx.x;
  const int chunk = total >> 3;
  const int swz   = ((total & 7) == 0) ? ((lin & 7) * chunk + (lin >> 3)) : lin;
  const int n0   = (swz % nbx) * 128;
  const int m0   = (swz / nbx) * 128;
  const int t    = threadIdx.x;
  const int w    = t >> 6;
  const int lane = t & 63;
  const int wm   = (w >> 1) * 64;
  const int wn   = (w & 1) * 64;
  const int lr   = lane & 15;
  const int lq   = lane >> 4;

  f32x4 acc[4][4];
  #pragma unroll
  for (int i = 0; i < 4; i++)
    #pragma unroll
    for (int j = 0; j < 4; j++)
      acc[i][j] = (f32x4){0.f, 0.f, 0.f, 0.f};

  auto stage = [&](int buf, int kk0) {
    #pragma unroll
    for (int j = 0; j < 4; j++) {
      int s  = t + 256 * j;
      int r  = s >> 3;
      int cs = (s & 7) ^ (r & 7);
      load_lds16(A + (size_t)(m0 + r) * K + kk0 + cs * 8, &sA[buf][s * 8]);
      int wr = n0 + r; wr = wr < N ? wr : N - 1;
      load_lds16(W + (size_t)wr * K + kk0 + cs * 8, &sW[buf][s * 8]);
    }
  };

  stage(0, 0);                          // 8 loads in flight

  int cur = 0;
  for (int k0 = 0; k0 < K; k0 += 64) {
    const bool more = (k0 + 64 < K);
    if (more) stage(cur ^ 1, k0 + 64);  // +8 loads; do NOT wait on these now
    if (more) asm volatile("s_waitcnt vmcnt(8)" ::: "memory");
    else      asm volatile("s_waitcnt vmcnt(0)" ::: "memory");
    __builtin_amdgcn_s_barrier();       // all waves: buffer `cur` fully landed
    asm volatile("" ::: "memory");

    const bhalf* pA = sA[cur];
    const bhalf* pW = sW[cur];
    #pragma unroll
    for (int kk = 0; kk < 2; kk++) {
      bhalf8 af[4], bfr[4];
      #pragma unroll
      for (int i = 0; i < 4; i++) {
        int r = wm + i * 16 + lr;
        int c = (kk * 4 + lq) ^ (r & 7);
        af[i] = *(const bhalf8*)(pA + r * 64 + c * 8);
      }
      #pragma unroll
      for (int j = 0; j < 4; j++) {
        int r = wn + j * 16 + lr;
        int c = (kk * 4 + lq) ^ (r & 7);
        bfr[j] = *(const bhalf8*)(pW + r * 64 + c * 8);
      }
      #pragma unroll
      for (int i = 0; i < 4; i++)
        #pragma unroll
        for (int j = 0; j < 4; j++)
          acc[i][j] = __builtin_amdgcn_mfma_f32_16x16x32_bf16(af[i], bfr[j], acc[i][j], 0, 0, 0);
    }
    __builtin_amdgcn_s_barrier();       // all waves' ds_reads of `cur` retired
    asm volatile("" ::: "memory");
    cur ^= 1;
  }

  #pragma unroll
  for (int i = 0; i < 4; i++) {
    #pragma unroll
    for (int j = 0; j < 4; j++) {
      #pragma unroll
      for (int r = 0; r < 4; r++) {
        int m = m0 + wm + i * 16 + lq * 4 + r;
        int n = n0 + wn + j * 16 + lr;
        if (n < N) {
          float v = acc[i][j][r];
          size_t idx = (size_t)m * ldout + n;
          if (EPI == 0) {
            outB[idx] = __float2bfloat16(v);
          } else {
            v += __bfloat162float(bias[n]);
            outB[idx] = __float2bfloat16(0.5f * v * (1.0f + erff(v * 0.70710678118654752f)));
          }
        }
      }
    }
  }
}

// ---------------------------------------------------------------------------
// EXPERIMENT (round 5): GEMM 128x128, BK=32, double-buffered counted-vmcnt,
// 32 KB LDS -> 4 blocks/CU. Tests TLP x prefetch at the same shape as the
// 256^2 control (ffn1). 32 K-iters; per tile: 4 gloads/thread, vmcnt(4),
// 16 MFMA, 8 ds_read_b128, 2 raw barriers. Requires M%128==0, N%128==0.
// ---------------------------------------------------------------------------
template<int EPI>
__global__ __launch_bounds__(256, 4)
void gemm128_bk32(const bf16* __restrict__ A, const bf16* __restrict__ W,
                  int M, int N, int K, int ldout,
                  bf16* __restrict__ outB,
                  const bf16* __restrict__ bias)
{
  __shared__ __align__(16) bhalf sA[2][128 * 32];
  __shared__ __align__(16) bhalf sW[2][128 * 32];
  const int nbx   = gridDim.x;
  const int total = nbx * gridDim.y;
  const int lin   = blockIdx.y * nbx + blockIdx.x;
  const int chunk = total >> 3;
  const int swz   = ((total & 7) == 0) ? ((lin & 7) * chunk + (lin >> 3)) : lin;
  const int n0   = (swz % nbx) * 128;
  const int m0   = (swz / nbx) * 128;
  const int t    = threadIdx.x;
  const int w    = t >> 6;
  const int lane = t & 63;
  const int wm   = (w >> 1) * 64;
  const int wn   = (w & 1) * 64;
  const int lr   = lane & 15;
  const int lq   = lane >> 4;

  f32x4 acc[4][4];
  #pragma unroll
  for (int i = 0; i < 4; i++)
    #pragma unroll
    for (int j = 0; j < 4; j++)
      acc[i][j] = (f32x4){0.f, 0.f, 0.f, 0.f};

  // 2 loads/thread per operand per K-tile (128 rows x 4 chunks of 16B).
  auto stage = [&](int buf, int kk0) {
    #pragma unroll
    for (int j = 0; j < 2; j++) {
      int s  = t + 256 * j;            // 0..511 : 128 rows x 4 chunks
      int r  = s >> 2;
      int cs = (s & 3) ^ (r & 3);
      load_lds16(A + (size_t)(m0 + r) * K + kk0 + cs * 8, &sA[buf][s * 8]);
      load_lds16(W + (size_t)(n0 + r) * K + kk0 + cs * 8, &sW[buf][s * 8]);
    }
  };

  stage(0, 0);                          // 4 loads in flight

  int cur = 0;
  for (int k0 = 0; k0 < K; k0 += 32) {
    const bool more = (k0 + 32 < K);
    if (more) stage(cur ^ 1, k0 + 32);  // +4 loads; keep flying across barriers
    if (more) asm volatile("s_waitcnt vmcnt(4)" ::: "memory");
    else      asm volatile("s_waitcnt vmcnt(0)" ::: "memory");
    __builtin_amdgcn_s_barrier();       // buffer `cur` fully landed, all waves
    asm volatile("" ::: "memory");

    const bhalf* pA = sA[cur];
    const bhalf* pW = sW[cur];
    bhalf8 af[4], bfr[4];
    #pragma unroll
    for (int i = 0; i < 4; i++) {
      int r = wm + i * 16 + lr;
      int c = lq ^ (r & 3);
      af[i] = *(const bhalf8*)(pA + r * 32 + c * 8);
    }
    #pragma unroll
    for (int j = 0; j < 4; j++) {
      int r = wn + j * 16 + lr;
      int c = lq ^ (r & 3);
      bfr[j] = *(const bhalf8*)(pW + r * 32 + c * 8);
    }
    #pragma unroll
    for (int i = 0; i < 4; i++)
      #pragma unroll
      for (int j = 0; j < 4; j++)
        acc[i][j] = __builtin_amdgcn_mfma_f32_16x16x32_bf16(af[i], bfr[j], acc[i][j], 0, 0, 0);

    __builtin_amdgcn_s_barrier();       // all reads of `cur` retired
    asm volatile("" ::: "memory");
    cur ^= 1;
  }

  #pragma unroll
  for (int i = 0; i < 4; i++) {
    #pragma unroll
    for (int j = 0; j < 4; j++) {
      #pragma unroll
      for (int r = 0; r < 4; r++) {
        int m = m0 + wm + i * 16 + lq * 4 + r;
        int n = n0 + wn + j * 16 + lr;
        float v = acc[i][j][r];
        size_t idx = (size_t)m * ldout + n;
        if (EPI == 0) {
          outB[idx] = __float2bfloat16(v);
        } else {
          v += __bfloat162float(bias[n]);
          outB[idx] = __float2bfloat16(0.5f * v * (1.0f + erff(v * 0.70710678118654752f)));
        }
      }
    }
  }
}

// ---------------------------------------------------------------------------
// CONTROL: GEMM 256x256, BK=64, 512 threads (8 waves, 2m x 4n), XOR-swizzled
// LDS, double-buffered, counted vmcnt(8), 2 barriers/K-tile — the round-2
// validated loop (round-4's coarse 4-phase split regressed; reverted).
// Requires M%256==0, N%256==0. ldout decouples output stride.
// ---------------------------------------------------------------------------
template<int EPI>
__global__ __launch_bounds__(512, 2)
void gemm256_bt(const bf16* __restrict__ A, const bf16* __restrict__ W,
                int M, int N, int K, int ldout,
                bf16* __restrict__ outB,
                const bf16* __restrict__ bias)
{
  __shared__ __align__(16) bhalf sA[2][256 * 64];
  __shared__ __align__(16) bhalf sW[2][256 * 64];
  const int nbx   = gridDim.x;
  const int total = nbx * gridDim.y;
  const int lin   = blockIdx.y * nbx + blockIdx.x;
  const int chunk = total >> 3;
  const int swz   = ((total & 7) == 0) ? ((lin & 7) * chunk + (lin >> 3)) : lin;
  const int n0   = (swz % nbx) * 256;
  const int m0   = (swz / nbx) * 256;
  const int t    = threadIdx.x;
  const int w    = t >> 6;
  const int lane = t & 63;
  const int wm   = (w >> 2) * 128;     // 2 wave-rows of 128
  const int wn   = (w & 3) * 64;       // 4 wave-cols of 64
  const int lr   = lane & 15;
  const int lq   = lane >> 4;

  f32x4 acc[8][4];
  #pragma unroll
  for (int i = 0; i < 8; i++)
    #pragma unroll
    for (int j = 0; j < 4; j++)
      acc[i][j] = (f32x4){0.f, 0.f, 0.f, 0.f};

  auto stage = [&](int buf, int kk0) {
    #pragma unroll
    for (int j = 0; j < 4; j++) {
      int s  = t + 512 * j;            // 0..2047 : 256 rows x 8 chunks
      int r  = s >> 3;
      int cs = (s & 7) ^ (r & 7);
      load_lds16(A + (size_t)(m0 + r) * K + kk0 + cs * 8, &sA[buf][s * 8]);
    }
    #pragma unroll
    for (int j = 0; j < 4; j++) {
      int s  = t + 512 * j;
      int r  = s >> 3;
      int cs = (s & 7) ^ (r & 7);
      load_lds16(W + (size_t)(n0 + r) * K + kk0 + cs * 8, &sW[buf][s * 8]);
    }
  };

  stage(0, 0);                          // 8 loads in flight

  int cur = 0;
  for (int k0 = 0; k0 < K; k0 += 64) {
    const bool more = (k0 + 64 < K);
    if (more) stage(cur ^ 1, k0 + 64);  // +8 loads; keep them flying
    if (more) asm volatile("s_waitcnt vmcnt(8)" ::: "memory");
    else      asm volatile("s_waitcnt vmcnt(0)" ::: "memory");
    __builtin_amdgcn_s_barrier();       // buffer `cur` fully landed, all waves
    asm volatile("" ::: "memory");

    const bhalf* pA = sA[cur];
    const bhalf* pW = sW[cur];
    #pragma unroll
    for (int kk = 0; kk < 2; kk++) {
      bhalf8 af[8], bfr[4];
      #pragma unroll
      for (int i = 0; i < 8; i++) {
        int r = wm + i * 16 + lr;
        int c = (kk * 4 + lq) ^ (r & 7);
        af[i] = *(const bhalf8*)(pA + r * 64 + c * 8);
      }
      #pragma unroll
      for (int j = 0; j < 4; j++) {
        int r = wn + j * 16 + lr;
        int c = (kk * 4 + lq) ^ (r & 7);
        bfr[j] = *(const bhalf8*)(pW + r * 64 + c * 8);
      }
      #pragma unroll
      for (int i = 0; i < 8; i++)
        #pragma unroll
        for (int j = 0; j < 4; j++)
          acc[i][j] = __builtin_amdgcn_mfma_f32_16x16x32_bf16(af[i], bfr[j], acc[i][j], 0, 0, 0);
    }
    __builtin_amdgcn_s_barrier();
    asm volatile("" ::: "memory");
    cur ^= 1;
  }

  #pragma unroll
  for (int i = 0; i < 8; i++) {
    #pragma unroll
    for (int j = 0; j < 4; j++) {
      #pragma unroll
      for (int r = 0; r < 4; r++) {
        int m = m0 + wm + i * 16 + lq * 4 + r;
        int n = n0 + wn + j * 16 + lr;
        float v = acc[i][j][r];
        size_t idx = (size_t)m * ldout + n;
        if (EPI == 0) {
          outB[idx] = __float2bfloat16(v);
        } else {
          v += __bfloat162float(bias[n]);
          outB[idx] = __float2bfloat16(0.5f * v * (1.0f + erff(v * 0.70710678118654752f)));
        }
      }
    }
  }
}

// ---------------------------------------------------------------------------
// Skinny GEMM 64x128 tile, split-K=SK (N=1024): grid = 512*SK blocks,
// fp32 partials; epilogues live in the reduce kernels.
// ---------------------------------------------------------------------------
struct SkParts4 { float* p[4]; };

template<int SK>
__global__ __launch_bounds__(256, 4)
void gemm_skinny_sk(const bf16* __restrict__ A, const bf16* __restrict__ W,
                    int M, int N, int K, SkParts4 parts)
{
  __shared__ __align__(16) bhalf sA[64 * 64];
  __shared__ __align__(16) bhalf sW[128 * 64];
  const int id   = blockIdx.x;
  const int z    = id >> 9;            // split index (grid = 512*SK)
  const int id9  = id & 511;
  const int hi   = id9 >> 6;
  const int rem  = id9 & 63;
  const int jn   = rem >> 3;
  const int mi   = hi * 8 + (rem & 7);
  const int m0   = mi * 64;
  const int n0   = jn * 128;
  const int t    = threadIdx.x;
  const int w    = t >> 6;
  const int lane = t & 63;
  const int wm   = (w >> 1) * 32;
  const int wn   = (w & 1) * 64;
  const int lr   = lane & 15;
  const int lq   = lane >> 4;

  f32x4 acc[2][4];
  #pragma unroll
  for (int i = 0; i < 2; i++)
    #pragma unroll
    for (int j = 0; j < 4; j++)
      acc[i][j] = (f32x4){0.f, 0.f, 0.f, 0.f};

  const int kh = K / SK;
  const int kend = z * kh + kh;
  for (int k0 = z * kh; k0 < kend; k0 += 64) {
    #pragma unroll
    for (int j = 0; j < 2; j++) {
      int s  = t + 256 * j;
      int r  = s >> 3;
      int cs = (s & 7) ^ (r & 7);
      load_lds16(A + (size_t)(m0 + r) * K + k0 + cs * 8, sA + s * 8);
    }
    #pragma unroll
    for (int j = 0; j < 4; j++) {
      int s  = t + 256 * j;
      int r  = s >> 3;
      int cs = (s & 7) ^ (r & 7);
      load_lds16(W + (size_t)(n0 + r) * K + k0 + cs * 8, sW + s * 8);
    }
    __syncthreads();
    #pragma unroll
    for (int kk = 0; kk < 2; kk++) {
      bhalf8 af[2], bfr[4];
      #pragma unroll
      for (int i = 0; i < 2; i++) {
        int r = wm + i * 16 + lr;
        int c = (kk * 4 + lq) ^ (r & 7);
        af[i] = *(const bhalf8*)(sA + r * 64 + c * 8);
      }
      #pragma unroll
      for (int j = 0; j < 4; j++) {
        int r = wn + j * 16 + lr;
        int c = (kk * 4 + lq) ^ (r & 7);
        bfr[j] = *(const bhalf8*)(sW + r * 64 + c * 8);
      }
      #pragma unroll
      for (int i = 0; i < 2; i++)
        #pragma unroll
        for (int j = 0; j < 4; j++)
          acc[i][j] = __builtin_amdgcn_mfma_f32_16x16x32_bf16(af[i], bfr[j], acc[i][j], 0, 0, 0);
    }
    __syncthreads();
  }

  float* out = parts.p[z];
  #pragma unroll
  for (int i = 0; i < 2; i++)
    #pragma unroll
    for (int j = 0; j < 4; j++)
      #pragma unroll
      for (int r = 0; r < 4; r++) {
        int m = m0 + wm + i * 16 + lq * 4 + r;
        int n = n0 + wn + j * 16 + lr;
        out[(size_t)m * N + n] = acc[i][j][r];
      }
}

// ---------------------------------------------------------------------------
// out_proj reduce + residual + FULL ln2, one block per row:
//   x2f = p0 + p1 + resB;  hln = LN(x2f)*w+b (bf16)
// ---------------------------------------------------------------------------
__global__ __launch_bounds__(256)
void reduce_out_ln2_kernel(const float* __restrict__ p0, const float* __restrict__ p1,
                           const bf16* __restrict__ resB, float* __restrict__ x2f,
                           const bf16* __restrict__ w, const bf16* __restrict__ b,
                           bf16* __restrict__ hln)
{
  int row = blockIdx.x, t = threadIdx.x;
  int i = row * 256 + t;
  __shared__ float rs[4], rq[4];
  f32x4 a = ((const f32x4*)p0)[i];
  f32x4 bb = ((const f32x4*)p1)[i];
  u16x4 r = ((const u16x4*)resB)[i];
  f32x4 o;
  float s = 0.f, ss = 0.f;
  #pragma unroll
  for (int j = 0; j < 4; j++) {
    o[j] = a[j] + bb[j] + bf2f(r[j]);
    s += o[j]; ss += o[j] * o[j];
  }
  ((f32x4*)x2f)[i] = o;
  #pragma unroll
  for (int off = 32; off; off >>= 1) { s += __shfl_down(s, off); ss += __shfl_down(ss, off); }
  if ((t & 63) == 0) { rs[t >> 6] = s; rq[t >> 6] = ss; }
  __syncthreads();
  float S = rs[0] + rs[1] + rs[2] + rs[3];
  float Q = rq[0] + rq[1] + rq[2] + rq[3];
  float mean = S * (1.f / D_MODEL);
  float rstd = rsqrtf(Q * (1.f / D_MODEL) - mean * mean + 1e-5f);
  u16x4 wv = ((const u16x4*)w)[t];
  u16x4 bv = ((const u16x4*)b)[t];
  u16x4 ov;
  #pragma unroll
  for (int j = 0; j < 4; j++)
    ov[j] = f2bbits((o[j] - mean) * rstd * bf2f(wv[j]) + bf2f(bv[j]));
  ((u16x4*)hln)[i] = ov;
}

// ---------------------------------------------------------------------------
// ffn2 reduce: d_out = p0+p1+p2+p3 + bias + resF (dtype per flag)
// ---------------------------------------------------------------------------
__global__ __launch_bounds__(256)
void reduce_ffn_kernel(const float* __restrict__ p0, const float* __restrict__ p1,
                       const float* __restrict__ p2, const float* __restrict__ p3,
                       const bf16* __restrict__ bias, const float* __restrict__ resF,
                       void* __restrict__ outp, const int* __restrict__ flagp)
{
  int i = blockIdx.x * 256 + threadIdx.x;
  int n4 = i & (D_MODEL / 4 - 1);
  f32x4 v0 = ((const f32x4*)p0)[i];
  f32x4 v1 = ((const f32x4*)p1)[i];
  f32x4 v2 = ((const f32x4*)p2)[i];
  f32x4 v3 = ((const f32x4*)p3)[i];
  f32x4 rf = ((const f32x4*)resF)[i];
  u16x4 bb = ((const u16x4*)bias)[n4];
  f32x4 o;
  #pragma unroll
  for (int j = 0; j < 4; j++)
    o[j] = ((v0[j] + v1[j]) + (v2[j] + v3[j])) + rf[j] + bf2f(bb[j]);
  if (*flagp) {
    ((f32x4*)outp)[i] = o;
  } else {
    u16x4 ov;
    #pragma unroll
    for (int j = 0; j < 4; j++) ov[j] = f2bbits(o[j]);
    ((u16x4*)outp)[i] = ov;
  }
}

// ---------------------------------------------------------------------------
// Fused ln0 + ln1; reads x directly from d_in (fp32/bf16 per flag); float4.
// ---------------------------------------------------------------------------
__global__ __launch_bounds__(256)
void ln01_kernel(const void* __restrict__ xin, const int* __restrict__ flagp,
                 const bf16* __restrict__ w0, const bf16* __restrict__ b0,
                 const bf16* __restrict__ w1, const bf16* __restrict__ b1,
                 bf16* __restrict__ x0o, bf16* __restrict__ x1o)
{
  int row = blockIdx.x, t = threadIdx.x;
  int i = row * 256 + t;
  __shared__ float rs[4], rq[4];
  float v[4], s = 0.f, ss = 0.f;
  if (*flagp) {
    f32x4 xv = ((const f32x4*)xin)[i];
    #pragma unroll
    for (int j = 0; j < 4; j++) v[j] = xv[j];
  } else {
    u16x4 xv = ((const u16x4*)xin)[i];
    #pragma unroll
    for (int j = 0; j < 4; j++) v[j] = bf2f(xv[j]);
  }
  #pragma unroll
  for (int j = 0; j < 4; j++) { s += v[j]; ss += v[j] * v[j]; }
  #pragma unroll
  for (int o = 32; o; o >>= 1) { s += __shfl_down(s, o); ss += __shfl_down(ss, o); }
  if ((t & 63) == 0) { rs[t >> 6] = s; rq[t >> 6] = ss; }
  __syncthreads();
  float S = rs[0] + rs[1] + rs[2] + rs[3];
  float Q = rq[0] + rq[1] + rq[2] + rq[3];
  float mean = S * (1.f / D_MODEL);
  float rstd = rsqrtf(Q * (1.f / D_MODEL) - mean * mean + 1e-5f);
  u16x4 w0v = ((const u16x4*)w0)[t], b0v = ((const u16x4*)b0)[t];
  float u[4]; s = 0.f; ss = 0.f;
  u16x4 o0;
  #pragma unroll
  for (int j = 0; j < 4; j++) {
    u[j] = (v[j] - mean) * rstd * bf2f(w0v[j]) + bf2f(b0v[j]);
    s += u[j]; ss += u[j] * u[j];
    o0[j] = f2bbits(u[j]);
  }
  ((u16x4*)x0o)[i] = o0;
  __syncthreads();
  #pragma unroll
  for (int o = 32; o; o >>= 1) { s += __shfl_down(s, o); ss += __shfl_down(ss, o); }
  if ((t & 63) == 0) { rs[t >> 6] = s; rq[t >> 6] = ss; }
  __syncthreads();
  S = rs[0] + rs[1] + rs[2] + rs[3];
  Q = rq[0] + rq[1] + rq[2] + rq[3];
  mean = S * (1.f / D_MODEL);
  rstd = rsqrtf(Q * (1.f / D_MODEL) - mean * mean + 1e-5f);
  u16x4 w1v = ((const u16x4*)w1)[t], b1v = ((const u16x4*)b1)[t];
  u16x4 o1;
  #pragma unroll
  for (int j = 0; j < 4; j++)
    o1[j] = f2bbits((u[j] - mean) * rstd * bf2f(w1v[j]) + bf2f(b1v[j]));
  ((u16x4*)x1o)[i] = o1;
}

// ---------------------------------------------------------------------------
// Causal depthwise conv (k=4) + SiLU -> bf16 xact, vectorized 8 ch/thread.
// Grid dim3(2, NROWS); block.x=1 tail threads compute dt/lda.
// ---------------------------------------------------------------------------
__device__ __forceinline__ void conv8(const bf16* __restrict__ zxb,
                                      const bf16* __restrict__ cw,
                                      const bf16* __restrict__ cb,
                                      bf16* __restrict__ xact, int row, int c0)
{
  int l = row & (SEQ - 1);
  float acc[8];
  {
    bhalf8 cbv = *(const bhalf8*)(cb + c0);
    #pragma unroll
    for (int j = 0; j < 8; j++) acc[j] = (float)cbv[j];
  }
  bhalf wts[32];
  #pragma unroll
  for (int q = 0; q < 4; q++)
    *(bhalf8*)(wts + q * 8) = *(const bhalf8*)(cw + c0 * 4 + q * 8);
  #pragma unroll
  for (int k = 0; k < 4; k++) {
    int lt = l - 3 + k;
    if (lt >= 0) {
      bhalf8 xv = *(const bhalf8*)(zxb + (size_t)(row - 3 + k) * D_IN_PROJ + D_INNER + c0);
      #pragma unroll
      for (int j = 0; j < 8; j++)
        acc[j] = fmaf((float)xv[j], (float)wts[j * 4 + k], acc[j]);
    }
  }
  bhalf8 o;
  #pragma unroll
  for (int j = 0; j < 8; j++) {
    float a = acc[j];
    o[j] = (bhalf)(a / (1.f + expf(-a)));
  }
  *(bhalf8*)(xact + (size_t)row * CONV_DIM + c0) = o;
}

__global__ __launch_bounds__(256)
void conv_silu_dt_kernel(const bf16* __restrict__ zxb, const bf16* __restrict__ cw,
                         const bf16* __restrict__ cb, bf16* __restrict__ xact,
                         const bf16* __restrict__ dtb, const bf16* __restrict__ alog,
                         float* __restrict__ dts, float* __restrict__ ldab)
{
  const int row = blockIdx.y;
  const int t = threadIdx.x;
  if (blockIdx.x == 0) {
    conv8(zxb, cw, cb, xact, row, t * 8);
  } else {
    if (t < 16) {
      conv8(zxb, cw, cb, xact, row, 2048 + t * 8);
    } else if (t < 48) {
      int h = t - 16;
      float v = __bfloat162float(zxb[(size_t)row * D_IN_PROJ + (D_INNER + CONV_DIM) + h]) +
                __bfloat162float(dtb[h]);
      float sp = (v > 20.f) ? v : log1pf(expf(v));
      dts[row * NHEADS + h] = sp;
      ldab[row * NHEADS + h] = -sp * expf(__bfloat162float(alog[h]));
    }
  }
}

// ---------------------------------------------------------------------------
// MFMA chunk scan, pass 1 (chunk states).
// ---------------------------------------------------------------------------
__global__ __launch_bounds__(256)
void scan_state_kernel(const bf16* __restrict__ xact, const float* __restrict__ dts,
                       const float* __restrict__ ldab, bf16* __restrict__ Sbuf,
                       float* __restrict__ acb)
{
  __shared__ __align__(16) bf16 wBT[64][72];
  __shared__ __align__(16) bf16 XT[64][72];
  __shared__ float lsS[64], dtS[64];
  const int bid = blockIdx.x;
  const int bh = bid & 63, c = bid >> 6;
  const int b = bh >> 5, h = bh & 31;
  const int t0 = c * TC;
  const int tid = threadIdx.x;
  const int w = tid >> 6, lane = tid & 63;
  const int lr = lane & 15, lq = lane >> 4;

  if (w == 0) {
    float v = ldab[(size_t)(b * SEQ + t0 + lane) * NHEADS + h];
    #pragma unroll
    for (int o = 1; o < 64; o <<= 1) {
      float up = __shfl_up(v, o);
      if (lane >= o) v += up;
    }
    lsS[lane] = v;
    dtS[lane] = dts[(size_t)(b * SEQ + t0 + lane) * NHEADS + h];
  }
  __syncthreads();
  const float lsT = lsS[63];
  {
    int nn = tid & 63, u0 = (tid >> 6) * 16;
    for (int i = 0; i < 16; i++) {
      int u = u0 + i;
      const bf16* rowp = xact + (size_t)(b * SEQ + t0 + u) * CONV_DIM;
      float wgt = dtS[u] * __expf(lsT - lsS[u]);
      wBT[nn][u] = __float2bfloat16(__bfloat162float(rowp[D_INNER + nn]) * wgt);
      XT[nn][u]  = rowp[h * 64 + nn];
    }
  }
  __syncthreads();

  bhalf8 af0 = *(const bhalf8*)&wBT[16 * w + lr][lq * 8];
  bhalf8 af1 = *(const bhalf8*)&wBT[16 * w + lr][32 + lq * 8];
  bf16* sb = Sbuf + ((size_t)bh * NCH + c) * 4096;
  #pragma unroll
  for (int jt = 0; jt < 4; jt++) {
    bhalf8 xf0 = *(const bhalf8*)&XT[16 * jt + lr][lq * 8];
    bhalf8 xf1 = *(const bhalf8*)&XT[16 * jt + lr][32 + lq * 8];
    f32x4 acc = (f32x4){0.f, 0.f, 0.f, 0.f};
    acc = __builtin_amdgcn_mfma_f32_16x16x32_bf16(af0, xf0, acc, 0, 0, 0);
    acc = __builtin_amdgcn_mfma_f32_16x16x32_bf16(af1, xf1, acc, 0, 0, 0);
    #pragma unroll
    for (int r = 0; r < 4; r++) {
      int n = 16 * w + lq * 4 + r;
      int p = 16 * jt + lr;
      sb[p * 64 + n] = __float2bfloat16(acc[r]);
    }
  }
  if (tid == 0) acb[bh * NCH + c] = __expf(lsT);
}

// ---------------------------------------------------------------------------
// Pass 2: serial inter-chunk propagation (in-place).
// ---------------------------------------------------------------------------
__global__ __launch_bounds__(256)
void state_prop_kernel(bf16* __restrict__ Sbuf, const float* __restrict__ acb)
{
  const int bh = blockIdx.x >> 2, q = blockIdx.x & 3;
  const int t = threadIdx.x;
  bf16* sp = Sbuf + (size_t)bh * NCH * 4096 + q * 1024 + t;
  const float* ap = acb + bh * NCH;
  float h0 = 0.f, h1 = 0.f, h2 = 0.f, h3 = 0.f;
  for (int c = 0; c < NCH; c++) {
    bf16* pc = sp + (size_t)c * 4096;
    float s0 = __bfloat162float(pc[0]);
    float s1 = __bfloat162float(pc[256]);
    float s2 = __bfloat162float(pc[512]);
    float s3 = __bfloat162float(pc[768]);
    float a = ap[c];
    pc[0]   = __float2bfloat16(h0);
    pc[256] = __float2bfloat16(h1);
    pc[512] = __float2bfloat16(h2);
    pc[768] = __float2bfloat16(h3);
    h0 = fmaf(h0, a, s0); h1 = fmaf(h1, a, s1);
    h2 = fmaf(h2, a, s2); h3 = fmaf(h3, a, s3);
  }
}

// ---------------------------------------------------------------------------
// MFMA chunk scan, pass 3.
// ---------------------------------------------------------------------------
__global__ __launch_bounds__(256)
void scan_y_kernel(const bf16* __restrict__ xact, const float* __restrict__ dts,
                   const float* __restrict__ ldab, const bf16* __restrict__ Sbuf,
                   bf16* __restrict__ yfull)
{
  __shared__ __align__(16) bf16 Cs[64][72];
  __shared__ __align__(16) bf16 Bs[64][72];    // reused for M after G loop
  __shared__ __align__(16) bf16 XT[64][72];
  __shared__ __align__(16) bf16 HT[64][72];
  __shared__ float lsS[64], dtS[64];
  const int bid = blockIdx.x;
  const int bh = bid & 63, c = bid >> 6;
  const int b = bh >> 5, h = bh & 31;
  const int t0 = c * TC;
  const int tid = threadIdx.x;
  const int w = tid >> 6, lane = tid & 63;
  const int lr = lane & 15, lq = lane >> 4;

  if (w == 0) {
    float v = ldab[(size_t)(b * SEQ + t0 + lane) * NHEADS + h];
    #pragma unroll
    for (int o = 1; o < 64; o <<= 1) {
      float up = __shfl_up(v, o);
      if (lane >= o) v += up;
    }
    lsS[lane] = v;
    dtS[lane] = dts[(size_t)(b * SEQ + t0 + lane) * NHEADS + h];
  }
  {
    int nn = tid & 63, u0 = (tid >> 6) * 16;
    for (int i = 0; i < 16; i++) {
      int u = u0 + i;
      const bf16* rowp = xact + (size_t)(b * SEQ + t0 + u) * CONV_DIM;
      Bs[u][nn] = rowp[D_INNER + nn];
      Cs[u][nn] = rowp[D_INNER + 64 + nn];
      XT[nn][u] = rowp[h * 64 + nn];
    }
    const bf16* sb = Sbuf + ((size_t)bh * NCH + c) * 4096;
    for (int i = 0; i < 16; i++) {
      int e = tid + 256 * i;
      HT[e >> 6][e & 63] = sb[e];
    }
  }
  __syncthreads();

  bhalf8 cf0 = *(const bhalf8*)&Cs[16 * w + lr][lq * 8];
  bhalf8 cf1 = *(const bhalf8*)&Cs[16 * w + lr][32 + lq * 8];
  f32x4 accH[4];
  float mreg[4][4];
  #pragma unroll
  for (int jt = 0; jt < 4; jt++) {
    bhalf8 bf0 = *(const bhalf8*)&Bs[16 * jt + lr][lq * 8];
    bhalf8 bf1 = *(const bhalf8*)&Bs[16 * jt + lr][32 + lq * 8];
    f32x4 g = (f32x4){0.f, 0.f, 0.f, 0.f};
    g = __builtin_amdgcn_mfma_f32_16x16x32_bf16(cf0, bf0, g, 0, 0, 0);
    g = __builtin_amdgcn_mfma_f32_16x16x32_bf16(cf1, bf1, g, 0, 0, 0);
    bhalf8 hf0 = *(const bhalf8*)&HT[16 * jt + lr][lq * 8];
    bhalf8 hf1 = *(const bhalf8*)&HT[16 * jt + lr][32 + lq * 8];
    f32x4 ah = (f32x4){0.f, 0.f, 0.f, 0.f};
    ah = __builtin_amdgcn_mfma_f32_16x16x32_bf16(cf0, hf0, ah, 0, 0, 0);
    ah = __builtin_amdgcn_mfma_f32_16x16x32_bf16(cf1, hf1, ah, 0, 0, 0);
    accH[jt] = ah;
    #pragma unroll
    for (int r = 0; r < 4; r++) {
      int t = 16 * w + lq * 4 + r;
      int u = 16 * jt + lr;
      float m = 0.f;
      if (u <= t) m = g[r] * __expf(lsS[t] - lsS[u]) * dtS[u];
      mreg[jt][r] = m;
    }
  }
  __syncthreads();               // all Bs reads complete
  #pragma unroll
  for (int jt = 0; jt < 4; jt++)
    #pragma unroll
    for (int r = 0; r < 4; r++)
      Bs[16 * w + lq * 4 + r][16 * jt + lr] = __float2bfloat16(mreg[jt][r]);
  __syncthreads();

  bhalf8 mf0 = *(const bhalf8*)&Bs[16 * w + lr][lq * 8];
  bhalf8 mf1 = *(const bhalf8*)&Bs[16 * w + lr][32 + lq * 8];
  #pragma unroll
  for (int jt = 0; jt < 4; jt++) {
    bhalf8 xf0 = *(const bhalf8*)&XT[16 * jt + lr][lq * 8];
    bhalf8 xf1 = *(const bhalf8*)&XT[16 * jt + lr][32 + lq * 8];
    f32x4 acc = (f32x4){0.f, 0.f, 0.f, 0.f};
    acc = __builtin_amdgcn_mfma_f32_16x16x32_bf16(mf0, xf0, acc, 0, 0, 0);
    acc = __builtin_amdgcn_mfma_f32_16x16x32_bf16(mf1, xf1, acc, 0, 0, 0);
    #pragma unroll
    for (int r = 0; r < 4; r++) {
      int t = 16 * w + lq * 4 + r;
      int p = 16 * jt + lr;
      float y = acc[r] + __expf(lsS[t]) * accH[jt][r];
      yfull[(size_t)(b * SEQ + t0 + t) * D_INNER + h * 64 + p] = __float2bfloat16(y);
    }
  }
}

// ---------------------------------------------------------------------------
// y = yfull + D*x;  y *= silu(z);  RMSNorm * norm_w -> bf16.
// ---------------------------------------------------------------------------
__global__ __launch_bounds__(256)
void gate_rms_kernel(const bf16* __restrict__ yfull, const bf16* __restrict__ xact,
                     const bf16* __restrict__ zxb, const bf16* __restrict__ Dp,
                     const bf16* __restrict__ nw, bf16* __restrict__ yn)
{
  int row = blockIdx.x, t = threadIdx.x;
  int c0 = t * 8;
  __shared__ float rq[4];
  bhalf8 yv8 = *(const bhalf8*)(yfull + (size_t)row * D_INNER + c0);
  bhalf8 xv8 = *(const bhalf8*)(xact + (size_t)row * CONV_DIM + c0);
  bhalf8 zv8 = *(const bhalf8*)(zxb + (size_t)row * D_IN_PROJ + c0);
  float Dv = __bfloat162float(Dp[c0 >> 6]);
  float yv[8]; float ss = 0.f;
  #pragma unroll
  for (int j = 0; j < 8; j++) {
    float y = (float)yv8[j] + Dv * (float)xv8[j];
    float z = (float)zv8[j];
    yv[j] = y * (z / (1.f + expf(-z)));
    ss += yv[j] * yv[j];
  }
  #pragma unroll
  for (int o = 32; o; o >>= 1) ss += __shfl_down(ss, o);
  if ((t & 63) == 0) rq[t >> 6] = ss;
  __syncthreads();
  float tot = rq[0] + rq[1] + rq[2] + rq[3];
  float rr = rsqrtf(tot * (1.f / D_INNER) + 1e-5f);
  bhalf8 nv8 = *(const bhalf8*)(nw + c0);
  bhalf8 o;
  #pragma unroll
  for (int j = 0; j < 8; j++)
    o[j] = (bhalf)(yv[j] * rr * (float)nv8[j]);
  *(bhalf8*)(yn + (size_t)row * D_INNER + c0) = o;
}

// ---------------------------------------------------------------------------
extern "C" void kernel_launch(void* const* d_in, const int* in_sizes, int n_in,
                              void* d_out, int out_size, void* d_ws, size_t ws_size,
                              hipStream_t stream)
{
  char* ws = (char*)d_ws;
  bf16*  x1b   = (bf16*) (ws + 0);           //  [3->4]
  bf16*  Sbuf  = (bf16*) (ws + 0);           //  [7->9]   alias x1b (dead @4)
  bf16*  ynb   = (bf16*) (ws + 0);           //  [10->11] alias Sbuf
  float* pf0   = (float*)(ws + 0);           //  [14->14b] alias ynb
  bf16*  wproj = (bf16*) (ws + 16777216);    //  [2->4]
  float* acb   = (float*)(ws + 16777216);    //  [7->8]   alias wproj
  float* dtsb  = (float*)(ws + 16785408);    //  [5->9]   alias wproj
  float* ldab  = (float*)(ws + 17309696);    //  [5->9]   alias wproj
  float* pf1   = (float*)(ws + 16777216);    //  [14->14b] alias wproj region
  bf16*  wout  = (bf16*) (ws + 25493504);    //  [2->11]
  bf16*  w1c   = (bf16*) (ws + 29687808);    //  [2->13]
  bf16*  w2c   = (bf16*) (ws + 38076416);    //  [2->14]
  bf16*  ln0w  = (bf16*) (ws + 46465024);
  bf16*  ln0b  = (bf16*) (ws + 46467072);
  bf16*  ln1w  = (bf16*) (ws + 46469120);
  bf16*  ln1b  = (bf16*) (ws + 46471168);
  bf16*  ln2w  = (bf16*) (ws + 46473216);
  bf16*  ln2b  = (bf16*) (ws + 46475264);
  bf16*  convw = (bf16*) (ws + 46477312);
  bf16*  convb = (bf16*) (ws + 46494720);
  bf16*  dtb   = (bf16*) (ws + 46499072);
  bf16*  alog  = (bf16*) (ws + 46499136);
  bf16*  Dp    = (bf16*) (ws + 46499200);
  bf16*  normw = (bf16*) (ws + 46499264);
  bf16*  b1c   = (bf16*) (ws + 46503360);
  bf16*  b2c   = (bf16*) (ws + 46511552);
  int*   flag  = (int*)  (ws + 46513600);
  bf16*  x0b   = (bf16*) (ws + 46514176);    //  [3->11b]
  bf16*  zxb   = (bf16*) (ws + 54902784);    //  [4->10]
  float* x2f   = (float*)(ws + 54902784);    //  [11b->14b] alias zxb (ends 71.68M)
  float* pf3   = (float*)(ws + 71680000);    //  [14->14b] zxb tail (dead @10), ends 88.46M
  bf16*  xact  = (bf16*) (ws + 89767936);    //  [5->10]
  float* pout0 = (float*)(ws + 89767936);    //  [11->11b] alias xact
  float* pout1 = (float*)(ws + 106545152);   //  [11->11b]
  bf16*  gbuf  = (bf16*) (ws + 89767936);    //  [13->14] alias xact region
  bf16*  yfull = (bf16*) (ws + 125419520);   //  [9->10]
  bf16*  hln   = (bf16*) (ws + 125419520);   //  [11b->13] alias yfull
  float* pf2   = (float*)(ws + 125419520);   //  [14->14b] alias hln (dead @13)

  CvtArgs ca;
  void* dsts[NT] = { ln0w, ln0b, ln1w, ln1b, ln2w, ln2b, wproj, convw, convb,
                     dtb, alog, Dp, normw, wout, w1c, b1c, w2c, b2c };
  int cc = 0;
  ca.ccum[0] = 0;
  for (int i = 0; i < NT; i++) {
    ca.src[i] = d_in[i + 1];
    ca.dst[i] = dsts[i];
    ca.nel[i] = in_sizes[i + 1];
    cc += (in_sizes[i + 1] + 2047) / 2048;
    ca.ccum[i + 1] = cc;
  }
  cvt_kernel<<<cc, 256, 0, stream>>>(ca, (const unsigned short*)d_in[0], flag);

  ln01_kernel<<<NROWS, 256, 0, stream>>>(d_in[0], flag, ln0w, ln0b, ln1w, ln1b,
                                         x0b, x1b);

  // in_proj main: EXPERIMENT ARM — BK=32 128^2 dbuf counted, 4 blocks/CU
  // (1024 blocks). Tail (cols 4096..4255) on the BK=64 128^2 kernel.
  gemm128_bk32<0><<<dim3(32, 32), 256, 0, stream>>>(x1b, wproj, NROWS, 4096, D_MODEL,
                                                    D_IN_PROJ, zxb, nullptr);
  gemm_bt<0><<<dim3(2, 32), 256, 0, stream>>>(x1b, wproj + (size_t)4096 * D_MODEL,
                                              NROWS, 160, D_MODEL, D_IN_PROJ,
                                              zxb + 4096, nullptr);

  conv_silu_dt_kernel<<<dim3(2, NROWS), 256, 0, stream>>>(zxb, convw, convb, xact,
                                                          dtb, alog, dtsb, ldab);

  scan_state_kernel<<<NCH * 64, 256, 0, stream>>>(xact, dtsb, ldab, Sbuf, acb);
  state_prop_kernel<<<64 * 4, 256, 0, stream>>>(Sbuf, acb);
  scan_y_kernel<<<NCH * 64, 256, 0, stream>>>(xact, dtsb, ldab, Sbuf, yfull);

  gate_rms_kernel<<<NROWS, 256, 0, stream>>>(yfull, xact, zxb, Dp, normw, ynb);

  // out_proj: 64x128 split-K=2 -> partials, then fused reduce+residual+ln2
  SkParts4 po = { { pout0, pout1, pout0, pout0 } };
  gemm_skinny_sk<2><<<1024, 256, 0, stream>>>(ynb, wout, NROWS, D_MODEL, D_INNER, po);
  reduce_out_ln2_kernel<<<NROWS, 256, 0, stream>>>(pout0, pout1, x0b, x2f,
                                                   ln2w, ln2b, hln);

  // ffn1: CONTROL ARM — 256^2 counted-vmcnt 2-barrier loop (round-2 proven)
  gemm256_bt<2><<<dim3(16, 16), 512, 0, stream>>>(hln, w1c, NROWS, FFN_DIM, D_MODEL,
                                                  FFN_DIM, gbuf, b1c);

  // ffn2: 64x128 split-K=4 (2048 blocks, 8/CU) -> partials, then fused reduce
  SkParts4 pfp = { { pf0, pf1, pf2, pf3 } };
  gemm_skinny_sk<4><<<2048, 256, 0, stream>>>(gbuf, w2c, NROWS, D_MODEL, FFN_DIM, pfp);
  reduce_ffn_kernel<<<(NROWS * D_MODEL) / 1024, 256, 0, stream>>>(pf0, pf1, pf2, pf3,
                                                                  b2c, x2f, d_out, flag);
}

// Round 6
// 431.396 us; speedup vs baseline: 1.0525x; 1.0303x over previous
//
#include <hip/hip_runtime.h>
#include <hip/hip_bf16.h>
#include <math.h>

typedef __hip_bfloat16 bf16;
typedef __bf16 bhalf;
typedef bhalf bhalf8 __attribute__((ext_vector_type(8)));
typedef float f32x4 __attribute__((ext_vector_type(4)));
typedef unsigned short u16;
typedef u16 u16x4 __attribute__((ext_vector_type(4)));
typedef u16 u16x8 __attribute__((ext_vector_type(8)));

#define D_MODEL   1024
#define D_STATE   64
#define HEADDIM   64
#define D_INNER   2048
#define NHEADS    32
#define CONV_DIM  2176
#define D_IN_PROJ 4256
#define FFN_DIM   4096
#define BSZ       2
#define SEQ       2048
#define NROWS     (BSZ*SEQ)
#define TC        64
#define NCH       (SEQ/TC)

#define AS1 __attribute__((address_space(1)))
#define AS3 __attribute__((address_space(3)))
__device__ __forceinline__ void load_lds16(const void* g, void* l) {
  __builtin_amdgcn_global_load_lds((AS1 void*)g, (AS3 void*)l, 16, 0, 0);
}

__device__ __forceinline__ float bf2f(u16 u) {
  return __uint_as_float(((unsigned)u) << 16);
}
__device__ __forceinline__ u16 f2bbits(float f) {
  bf16 h = __float2bfloat16(f);
  return *(u16*)&h;
}

// ---------------------------------------------------------------------------
// Normalize weight inputs to bf16 copies; vectorized. Each block self-detects
// the input dtype. Block 0 publishes the flag for downstream consumers.
// ---------------------------------------------------------------------------
#define NT 18
struct CvtArgs {
  const void* src[NT];
  void*       dst[NT];
  int ccum[NT + 1];
  int nel[NT];
};

__global__ __launch_bounds__(256)
void cvt_kernel(CvtArgs a, const unsigned short* __restrict__ x0,
                int* __restrict__ flagp)
{
  __shared__ int sbad;
  if (threadIdx.x == 0) sbad = 0;
  __syncthreads();
  {
    float v = bf2f(x0[threadIdx.x]);
    if (!(fabsf(v) <= 1e6f)) sbad = 1;   // benign race, same value
  }
  __syncthreads();
  const int isf32 = sbad;
  if (blockIdx.x == 0 && threadIdx.x == 0) *flagp = isf32;

  int c = blockIdx.x;
  int ti = 0;
  while (c >= a.ccum[ti + 1]) ti++;
  int j = (c - a.ccum[ti]) * 2048 + threadIdx.x * 8;
  if (j >= a.nel[ti]) return;
  if (isf32) {
    const float* s = (const float*)a.src[ti];
    f32x4 v0 = *(const f32x4*)(s + j);
    f32x4 v1 = *(const f32x4*)(s + j + 4);
    u16x8 o;
    #pragma unroll
    for (int k = 0; k < 4; k++) { o[k] = f2bbits(v0[k]); o[k + 4] = f2bbits(v1[k]); }
    *(u16x8*)((u16*)a.dst[ti] + j) = o;
  } else {
    *(u16x8*)((u16*)a.dst[ti] + j) = *(const u16x8*)((const u16*)a.src[ti] + j);
  }
}

// ---------------------------------------------------------------------------
// GEMM 128x128, BK=64, XOR-swizzled LDS, double-buffered, counted vmcnt.
// Used for the in_proj 160-column tail (N=160, ldout=4256).
// EPI 0: store bf16   EPI 2: store bf16(gelu(acc+bias))
// ---------------------------------------------------------------------------
template<int EPI>
__global__ __launch_bounds__(256, 2)
void gemm_bt(const bf16* __restrict__ A, const bf16* __restrict__ W,
             int M, int N, int K, int ldout,
             bf16* __restrict__ outB,
             const bf16* __restrict__ bias)
{
  __shared__ __align__(16) bhalf sA[2][128 * 64];
  __shared__ __align__(16) bhalf sW[2][128 * 64];
  const int nbx   = gridDim.x;
  const int total = nbx * gridDim.y;
  const int lin   = blockIdx.y * nbx + blockIdx.x;
  const int chunk = total >> 3;
  const int swz   = ((total & 7) == 0) ? ((lin & 7) * chunk + (lin >> 3)) : lin;
  const int n0   = (swz % nbx) * 128;
  const int m0   = (swz / nbx) * 128;
  const int t    = threadIdx.x;
  const int w    = t >> 6;
  const int lane = t & 63;
  const int wm   = (w >> 1) * 64;
  const int wn   = (w & 1) * 64;
  const int lr   = lane & 15;
  const int lq   = lane >> 4;

  f32x4 acc[4][4];
  #pragma unroll
  for (int i = 0; i < 4; i++)
    #pragma unroll
    for (int j = 0; j < 4; j++)
      acc[i][j] = (f32x4){0.f, 0.f, 0.f, 0.f};

  auto stage = [&](int buf, int kk0) {
    #pragma unroll
    for (int j = 0; j < 4; j++) {
      int s  = t + 256 * j;
      int r  = s >> 3;
      int cs = (s & 7) ^ (r & 7);
      load_lds16(A + (size_t)(m0 + r) * K + kk0 + cs * 8, &sA[buf][s * 8]);
      int wr = n0 + r; wr = wr < N ? wr : N - 1;
      load_lds16(W + (size_t)wr * K + kk0 + cs * 8, &sW[buf][s * 8]);
    }
  };

  stage(0, 0);                          // 8 loads in flight

  int cur = 0;
  for (int k0 = 0; k0 < K; k0 += 64) {
    const bool more = (k0 + 64 < K);
    if (more) stage(cur ^ 1, k0 + 64);  // +8 loads; do NOT wait on these now
    if (more) asm volatile("s_waitcnt vmcnt(8)" ::: "memory");
    else      asm volatile("s_waitcnt vmcnt(0)" ::: "memory");
    __builtin_amdgcn_s_barrier();       // all waves: buffer `cur` fully landed
    asm volatile("" ::: "memory");

    const bhalf* pA = sA[cur];
    const bhalf* pW = sW[cur];
    #pragma unroll
    for (int kk = 0; kk < 2; kk++) {
      bhalf8 af[4], bfr[4];
      #pragma unroll
      for (int i = 0; i < 4; i++) {
        int r = wm + i * 16 + lr;
        int c = (kk * 4 + lq) ^ (r & 7);
        af[i] = *(const bhalf8*)(pA + r * 64 + c * 8);
      }
      #pragma unroll
      for (int j = 0; j < 4; j++) {
        int r = wn + j * 16 + lr;
        int c = (kk * 4 + lq) ^ (r & 7);
        bfr[j] = *(const bhalf8*)(pW + r * 64 + c * 8);
      }
      #pragma unroll
      for (int i = 0; i < 4; i++)
        #pragma unroll
        for (int j = 0; j < 4; j++)
          acc[i][j] = __builtin_amdgcn_mfma_f32_16x16x32_bf16(af[i], bfr[j], acc[i][j], 0, 0, 0);
    }
    __builtin_amdgcn_s_barrier();       // all waves' ds_reads of `cur` retired
    asm volatile("" ::: "memory");
    cur ^= 1;
  }

  #pragma unroll
  for (int i = 0; i < 4; i++) {
    #pragma unroll
    for (int j = 0; j < 4; j++) {
      #pragma unroll
      for (int r = 0; r < 4; r++) {
        int m = m0 + wm + i * 16 + lq * 4 + r;
        int n = n0 + wn + j * 16 + lr;
        if (n < N) {
          float v = acc[i][j][r];
          size_t idx = (size_t)m * ldout + n;
          if (EPI == 0) {
            outB[idx] = __float2bfloat16(v);
          } else {
            v += __bfloat162float(bias[n]);
            outB[idx] = __float2bfloat16(0.5f * v * (1.0f + erff(v * 0.70710678118654752f)));
          }
        }
      }
    }
  }
}

// ---------------------------------------------------------------------------
// WINNER (round 5 A/B): GEMM 128x128, BK=32, double-buffered counted-vmcnt,
// 32 KB LDS -> 4 blocks/CU. TLP x prefetch: at 4 resident blocks the CU
// scheduler covers L2/L3 miss bursts with other blocks' MFMA phases — the
// 1-2 block/CU structures (R2-R4, all ~62 us) could not. In_proj-main on
// this kernel dropped below the 60.7 us top-5 cutoff in round 5.
// Requires M%128==0, N%128==0.
// ---------------------------------------------------------------------------
template<int EPI>
__global__ __launch_bounds__(256, 4)
void gemm128_bk32(const bf16* __restrict__ A, const bf16* __restrict__ W,
                  int M, int N, int K, int ldout,
                  bf16* __restrict__ outB,
                  const bf16* __restrict__ bias)
{
  __shared__ __align__(16) bhalf sA[2][128 * 32];
  __shared__ __align__(16) bhalf sW[2][128 * 32];
  const int nbx   = gridDim.x;
  const int total = nbx * gridDim.y;
  const int lin   = blockIdx.y * nbx + blockIdx.x;
  const int chunk = total >> 3;
  const int swz   = ((total & 7) == 0) ? ((lin & 7) * chunk + (lin >> 3)) : lin;
  const int n0   = (swz % nbx) * 128;
  const int m0   = (swz / nbx) * 128;
  const int t    = threadIdx.x;
  const int w    = t >> 6;
  const int lane = t & 63;
  const int wm   = (w >> 1) * 64;
  const int wn   = (w & 1) * 64;
  const int lr   = lane & 15;
  const int lq   = lane >> 4;

  f32x4 acc[4][4];
  #pragma unroll
  for (int i = 0; i < 4; i++)
    #pragma unroll
    for (int j = 0; j < 4; j++)
      acc[i][j] = (f32x4){0.f, 0.f, 0.f, 0.f};

  // 2 loads/thread per operand per K-tile (128 rows x 4 chunks of 16B).
  auto stage = [&](int buf, int kk0) {
    #pragma unroll
    for (int j = 0; j < 2; j++) {
      int s  = t + 256 * j;            // 0..511 : 128 rows x 4 chunks
      int r  = s >> 2;
      int cs = (s & 3) ^ (r & 3);
      load_lds16(A + (size_t)(m0 + r) * K + kk0 + cs * 8, &sA[buf][s * 8]);
      load_lds16(W + (size_t)(n0 + r) * K + kk0 + cs * 8, &sW[buf][s * 8]);
    }
  };

  stage(0, 0);                          // 4 loads in flight

  int cur = 0;
  for (int k0 = 0; k0 < K; k0 += 32) {
    const bool more = (k0 + 32 < K);
    if (more) stage(cur ^ 1, k0 + 32);  // +4 loads; keep flying across barriers
    if (more) asm volatile("s_waitcnt vmcnt(4)" ::: "memory");
    else      asm volatile("s_waitcnt vmcnt(0)" ::: "memory");
    __builtin_amdgcn_s_barrier();       // buffer `cur` fully landed, all waves
    asm volatile("" ::: "memory");

    const bhalf* pA = sA[cur];
    const bhalf* pW = sW[cur];
    bhalf8 af[4], bfr[4];
    #pragma unroll
    for (int i = 0; i < 4; i++) {
      int r = wm + i * 16 + lr;
      int c = lq ^ (r & 3);
      af[i] = *(const bhalf8*)(pA + r * 32 + c * 8);
    }
    #pragma unroll
    for (int j = 0; j < 4; j++) {
      int r = wn + j * 16 + lr;
      int c = lq ^ (r & 3);
      bfr[j] = *(const bhalf8*)(pW + r * 32 + c * 8);
    }
    #pragma unroll
    for (int i = 0; i < 4; i++)
      #pragma unroll
      for (int j = 0; j < 4; j++)
        acc[i][j] = __builtin_amdgcn_mfma_f32_16x16x32_bf16(af[i], bfr[j], acc[i][j], 0, 0, 0);

    __builtin_amdgcn_s_barrier();       // all reads of `cur` retired
    asm volatile("" ::: "memory");
    cur ^= 1;
  }

  #pragma unroll
  for (int i = 0; i < 4; i++) {
    #pragma unroll
    for (int j = 0; j < 4; j++) {
      #pragma unroll
      for (int r = 0; r < 4; r++) {
        int m = m0 + wm + i * 16 + lq * 4 + r;
        int n = n0 + wn + j * 16 + lr;
        float v = acc[i][j][r];
        size_t idx = (size_t)m * ldout + n;
        if (EPI == 0) {
          outB[idx] = __float2bfloat16(v);
        } else {
          v += __bfloat162float(bias[n]);
          outB[idx] = __float2bfloat16(0.5f * v * (1.0f + erff(v * 0.70710678118654752f)));
        }
      }
    }
  }
}

// ---------------------------------------------------------------------------
// Skinny GEMM 64x128 tile, split-K=SK (N=1024): grid = 512*SK blocks,
// fp32 partials; epilogues live in the reduce kernels.
// ---------------------------------------------------------------------------
struct SkParts4 { float* p[4]; };

template<int SK>
__global__ __launch_bounds__(256, 4)
void gemm_skinny_sk(const bf16* __restrict__ A, const bf16* __restrict__ W,
                    int M, int N, int K, SkParts4 parts)
{
  __shared__ __align__(16) bhalf sA[64 * 64];
  __shared__ __align__(16) bhalf sW[128 * 64];
  const int id   = blockIdx.x;
  const int z    = id >> 9;            // split index (grid = 512*SK)
  const int id9  = id & 511;
  const int hi   = id9 >> 6;
  const int rem  = id9 & 63;
  const int jn   = rem >> 3;
  const int mi   = hi * 8 + (rem & 7);
  const int m0   = mi * 64;
  const int n0   = jn * 128;
  const int t    = threadIdx.x;
  const int w    = t >> 6;
  const int lane = t & 63;
  const int wm   = (w >> 1) * 32;
  const int wn   = (w & 1) * 64;
  const int lr   = lane & 15;
  const int lq   = lane >> 4;

  f32x4 acc[2][4];
  #pragma unroll
  for (int i = 0; i < 2; i++)
    #pragma unroll
    for (int j = 0; j < 4; j++)
      acc[i][j] = (f32x4){0.f, 0.f, 0.f, 0.f};

  const int kh = K / SK;
  const int kend = z * kh + kh;
  for (int k0 = z * kh; k0 < kend; k0 += 64) {
    #pragma unroll
    for (int j = 0; j < 2; j++) {
      int s  = t + 256 * j;
      int r  = s >> 3;
      int cs = (s & 7) ^ (r & 7);
      load_lds16(A + (size_t)(m0 + r) * K + k0 + cs * 8, sA + s * 8);
    }
    #pragma unroll
    for (int j = 0; j < 4; j++) {
      int s  = t + 256 * j;
      int r  = s >> 3;
      int cs = (s & 7) ^ (r & 7);
      load_lds16(W + (size_t)(n0 + r) * K + k0 + cs * 8, sW + s * 8);
    }
    __syncthreads();
    #pragma unroll
    for (int kk = 0; kk < 2; kk++) {
      bhalf8 af[2], bfr[4];
      #pragma unroll
      for (int i = 0; i < 2; i++) {
        int r = wm + i * 16 + lr;
        int c = (kk * 4 + lq) ^ (r & 7);
        af[i] = *(const bhalf8*)(sA + r * 64 + c * 8);
      }
      #pragma unroll
      for (int j = 0; j < 4; j++) {
        int r = wn + j * 16 + lr;
        int c = (kk * 4 + lq) ^ (r & 7);
        bfr[j] = *(const bhalf8*)(sW + r * 64 + c * 8);
      }
      #pragma unroll
      for (int i = 0; i < 2; i++)
        #pragma unroll
        for (int j = 0; j < 4; j++)
          acc[i][j] = __builtin_amdgcn_mfma_f32_16x16x32_bf16(af[i], bfr[j], acc[i][j], 0, 0, 0);
    }
    __syncthreads();
  }

  float* out = parts.p[z];
  #pragma unroll
  for (int i = 0; i < 2; i++)
    #pragma unroll
    for (int j = 0; j < 4; j++)
      #pragma unroll
      for (int r = 0; r < 4; r++) {
        int m = m0 + wm + i * 16 + lq * 4 + r;
        int n = n0 + wn + j * 16 + lr;
        out[(size_t)m * N + n] = acc[i][j][r];
      }
}

// ---------------------------------------------------------------------------
// out_proj reduce + residual + FULL ln2, one block per row:
//   x2f = p0 + p1 + resB;  hln = LN(x2f)*w+b (bf16)
// ---------------------------------------------------------------------------
__global__ __launch_bounds__(256)
void reduce_out_ln2_kernel(const float* __restrict__ p0, const float* __restrict__ p1,
                           const bf16* __restrict__ resB, float* __restrict__ x2f,
                           const bf16* __restrict__ w, const bf16* __restrict__ b,
                           bf16* __restrict__ hln)
{
  int row = blockIdx.x, t = threadIdx.x;
  int i = row * 256 + t;
  __shared__ float rs[4], rq[4];
  f32x4 a = ((const f32x4*)p0)[i];
  f32x4 bb = ((const f32x4*)p1)[i];
  u16x4 r = ((const u16x4*)resB)[i];
  f32x4 o;
  float s = 0.f, ss = 0.f;
  #pragma unroll
  for (int j = 0; j < 4; j++) {
    o[j] = a[j] + bb[j] + bf2f(r[j]);
    s += o[j]; ss += o[j] * o[j];
  }
  ((f32x4*)x2f)[i] = o;
  #pragma unroll
  for (int off = 32; off; off >>= 1) { s += __shfl_down(s, off); ss += __shfl_down(ss, off); }
  if ((t & 63) == 0) { rs[t >> 6] = s; rq[t >> 6] = ss; }
  __syncthreads();
  float S = rs[0] + rs[1] + rs[2] + rs[3];
  float Q = rq[0] + rq[1] + rq[2] + rq[3];
  float mean = S * (1.f / D_MODEL);
  float rstd = rsqrtf(Q * (1.f / D_MODEL) - mean * mean + 1e-5f);
  u16x4 wv = ((const u16x4*)w)[t];
  u16x4 bv = ((const u16x4*)b)[t];
  u16x4 ov;
  #pragma unroll
  for (int j = 0; j < 4; j++)
    ov[j] = f2bbits((o[j] - mean) * rstd * bf2f(wv[j]) + bf2f(bv[j]));
  ((u16x4*)hln)[i] = ov;
}

// ---------------------------------------------------------------------------
// ffn2 reduce: d_out = p0+p1+p2+p3 + bias + resF (dtype per flag)
// ---------------------------------------------------------------------------
__global__ __launch_bounds__(256)
void reduce_ffn_kernel(const float* __restrict__ p0, const float* __restrict__ p1,
                       const float* __restrict__ p2, const float* __restrict__ p3,
                       const bf16* __restrict__ bias, const float* __restrict__ resF,
                       void* __restrict__ outp, const int* __restrict__ flagp)
{
  int i = blockIdx.x * 256 + threadIdx.x;
  int n4 = i & (D_MODEL / 4 - 1);
  f32x4 v0 = ((const f32x4*)p0)[i];
  f32x4 v1 = ((const f32x4*)p1)[i];
  f32x4 v2 = ((const f32x4*)p2)[i];
  f32x4 v3 = ((const f32x4*)p3)[i];
  f32x4 rf = ((const f32x4*)resF)[i];
  u16x4 bb = ((const u16x4*)bias)[n4];
  f32x4 o;
  #pragma unroll
  for (int j = 0; j < 4; j++)
    o[j] = ((v0[j] + v1[j]) + (v2[j] + v3[j])) + rf[j] + bf2f(bb[j]);
  if (*flagp) {
    ((f32x4*)outp)[i] = o;
  } else {
    u16x4 ov;
    #pragma unroll
    for (int j = 0; j < 4; j++) ov[j] = f2bbits(o[j]);
    ((u16x4*)outp)[i] = ov;
  }
}

// ---------------------------------------------------------------------------
// Fused ln0 + ln1; reads x directly from d_in (fp32/bf16 per flag); float4.
// ---------------------------------------------------------------------------
__global__ __launch_bounds__(256)
void ln01_kernel(const void* __restrict__ xin, const int* __restrict__ flagp,
                 const bf16* __restrict__ w0, const bf16* __restrict__ b0,
                 const bf16* __restrict__ w1, const bf16* __restrict__ b1,
                 bf16* __restrict__ x0o, bf16* __restrict__ x1o)
{
  int row = blockIdx.x, t = threadIdx.x;
  int i = row * 256 + t;
  __shared__ float rs[4], rq[4];
  float v[4], s = 0.f, ss = 0.f;
  if (*flagp) {
    f32x4 xv = ((const f32x4*)xin)[i];
    #pragma unroll
    for (int j = 0; j < 4; j++) v[j] = xv[j];
  } else {
    u16x4 xv = ((const u16x4*)xin)[i];
    #pragma unroll
    for (int j = 0; j < 4; j++) v[j] = bf2f(xv[j]);
  }
  #pragma unroll
  for (int j = 0; j < 4; j++) { s += v[j]; ss += v[j] * v[j]; }
  #pragma unroll
  for (int o = 32; o; o >>= 1) { s += __shfl_down(s, o); ss += __shfl_down(ss, o); }
  if ((t & 63) == 0) { rs[t >> 6] = s; rq[t >> 6] = ss; }
  __syncthreads();
  float S = rs[0] + rs[1] + rs[2] + rs[3];
  float Q = rq[0] + rq[1] + rq[2] + rq[3];
  float mean = S * (1.f / D_MODEL);
  float rstd = rsqrtf(Q * (1.f / D_MODEL) - mean * mean + 1e-5f);
  u16x4 w0v = ((const u16x4*)w0)[t], b0v = ((const u16x4*)b0)[t];
  float u[4]; s = 0.f; ss = 0.f;
  u16x4 o0;
  #pragma unroll
  for (int j = 0; j < 4; j++) {
    u[j] = (v[j] - mean) * rstd * bf2f(w0v[j]) + bf2f(b0v[j]);
    s += u[j]; ss += u[j] * u[j];
    o0[j] = f2bbits(u[j]);
  }
  ((u16x4*)x0o)[i] = o0;
  __syncthreads();
  #pragma unroll
  for (int o = 32; o; o >>= 1) { s += __shfl_down(s, o); ss += __shfl_down(ss, o); }
  if ((t & 63) == 0) { rs[t >> 6] = s; rq[t >> 6] = ss; }
  __syncthreads();
  S = rs[0] + rs[1] + rs[2] + rs[3];
  Q = rq[0] + rq[1] + rq[2] + rq[3];
  mean = S * (1.f / D_MODEL);
  rstd = rsqrtf(Q * (1.f / D_MODEL) - mean * mean + 1e-5f);
  u16x4 w1v = ((const u16x4*)w1)[t], b1v = ((const u16x4*)b1)[t];
  u16x4 o1;
  #pragma unroll
  for (int j = 0; j < 4; j++)
    o1[j] = f2bbits((u[j] - mean) * rstd * bf2f(w1v[j]) + bf2f(b1v[j]));
  ((u16x4*)x1o)[i] = o1;
}

// ---------------------------------------------------------------------------
// Causal depthwise conv (k=4) + SiLU -> bf16 xact, vectorized 8 ch/thread.
// Grid dim3(2, NROWS); block.x=1 tail threads compute dt/lda.
// ---------------------------------------------------------------------------
__device__ __forceinline__ void conv8(const bf16* __restrict__ zxb,
                                      const bf16* __restrict__ cw,
                                      const bf16* __restrict__ cb,
                                      bf16* __restrict__ xact, int row, int c0)
{
  int l = row & (SEQ - 1);
  float acc[8];
  {
    bhalf8 cbv = *(const bhalf8*)(cb + c0);
    #pragma unroll
    for (int j = 0; j < 8; j++) acc[j] = (float)cbv[j];
  }
  bhalf wts[32];
  #pragma unroll
  for (int q = 0; q < 4; q++)
    *(bhalf8*)(wts + q * 8) = *(const bhalf8*)(cw + c0 * 4 + q * 8);
  #pragma unroll
  for (int k = 0; k < 4; k++) {
    int lt = l - 3 + k;
    if (lt >= 0) {
      bhalf8 xv = *(const bhalf8*)(zxb + (size_t)(row - 3 + k) * D_IN_PROJ + D_INNER + c0);
      #pragma unroll
      for (int j = 0; j < 8; j++)
        acc[j] = fmaf((float)xv[j], (float)wts[j * 4 + k], acc[j]);
    }
  }
  bhalf8 o;
  #pragma unroll
  for (int j = 0; j < 8; j++) {
    float a = acc[j];
    o[j] = (bhalf)(a / (1.f + expf(-a)));
  }
  *(bhalf8*)(xact + (size_t)row * CONV_DIM + c0) = o;
}

__global__ __launch_bounds__(256)
void conv_silu_dt_kernel(const bf16* __restrict__ zxb, const bf16* __restrict__ cw,
                         const bf16* __restrict__ cb, bf16* __restrict__ xact,
                         const bf16* __restrict__ dtb, const bf16* __restrict__ alog,
                         float* __restrict__ dts, float* __restrict__ ldab)
{
  const int row = blockIdx.y;
  const int t = threadIdx.x;
  if (blockIdx.x == 0) {
    conv8(zxb, cw, cb, xact, row, t * 8);
  } else {
    if (t < 16) {
      conv8(zxb, cw, cb, xact, row, 2048 + t * 8);
    } else if (t < 48) {
      int h = t - 16;
      float v = __bfloat162float(zxb[(size_t)row * D_IN_PROJ + (D_INNER + CONV_DIM) + h]) +
                __bfloat162float(dtb[h]);
      float sp = (v > 20.f) ? v : log1pf(expf(v));
      dts[row * NHEADS + h] = sp;
      ldab[row * NHEADS + h] = -sp * expf(__bfloat162float(alog[h]));
    }
  }
}

// ---------------------------------------------------------------------------
// MFMA chunk scan, pass 1 (chunk states).
// ---------------------------------------------------------------------------
__global__ __launch_bounds__(256)
void scan_state_kernel(const bf16* __restrict__ xact, const float* __restrict__ dts,
                       const float* __restrict__ ldab, bf16* __restrict__ Sbuf,
                       float* __restrict__ acb)
{
  __shared__ __align__(16) bf16 wBT[64][72];
  __shared__ __align__(16) bf16 XT[64][72];
  __shared__ float lsS[64], dtS[64];
  const int bid = blockIdx.x;
  const int bh = bid & 63, c = bid >> 6;
  const int b = bh >> 5, h = bh & 31;
  const int t0 = c * TC;
  const int tid = threadIdx.x;
  const int w = tid >> 6, lane = tid & 63;
  const int lr = lane & 15, lq = lane >> 4;

  if (w == 0) {
    float v = ldab[(size_t)(b * SEQ + t0 + lane) * NHEADS + h];
    #pragma unroll
    for (int o = 1; o < 64; o <<= 1) {
      float up = __shfl_up(v, o);
      if (lane >= o) v += up;
    }
    lsS[lane] = v;
    dtS[lane] = dts[(size_t)(b * SEQ + t0 + lane) * NHEADS + h];
  }
  __syncthreads();
  const float lsT = lsS[63];
  {
    int nn = tid & 63, u0 = (tid >> 6) * 16;
    for (int i = 0; i < 16; i++) {
      int u = u0 + i;
      const bf16* rowp = xact + (size_t)(b * SEQ + t0 + u) * CONV_DIM;
      float wgt = dtS[u] * __expf(lsT - lsS[u]);
      wBT[nn][u] = __float2bfloat16(__bfloat162float(rowp[D_INNER + nn]) * wgt);
      XT[nn][u]  = rowp[h * 64 + nn];
    }
  }
  __syncthreads();

  bhalf8 af0 = *(const bhalf8*)&wBT[16 * w + lr][lq * 8];
  bhalf8 af1 = *(const bhalf8*)&wBT[16 * w + lr][32 + lq * 8];
  bf16* sb = Sbuf + ((size_t)bh * NCH + c) * 4096;
  #pragma unroll
  for (int jt = 0; jt < 4; jt++) {
    bhalf8 xf0 = *(const bhalf8*)&XT[16 * jt + lr][lq * 8];
    bhalf8 xf1 = *(const bhalf8*)&XT[16 * jt + lr][32 + lq * 8];
    f32x4 acc = (f32x4){0.f, 0.f, 0.f, 0.f};
    acc = __builtin_amdgcn_mfma_f32_16x16x32_bf16(af0, xf0, acc, 0, 0, 0);
    acc = __builtin_amdgcn_mfma_f32_16x16x32_bf16(af1, xf1, acc, 0, 0, 0);
    #pragma unroll
    for (int r = 0; r < 4; r++) {
      int n = 16 * w + lq * 4 + r;
      int p = 16 * jt + lr;
      sb[p * 64 + n] = __float2bfloat16(acc[r]);
    }
  }
  if (tid == 0) acb[bh * NCH + c] = __expf(lsT);
}

// ---------------------------------------------------------------------------
// Pass 2: serial inter-chunk propagation (in-place).
// ---------------------------------------------------------------------------
__global__ __launch_bounds__(256)
void state_prop_kernel(bf16* __restrict__ Sbuf, const float* __restrict__ acb)
{
  const int bh = blockIdx.x >> 2, q = blockIdx.x & 3;
  const int t = threadIdx.x;
  bf16* sp = Sbuf + (size_t)bh * NCH * 4096 + q * 1024 + t;
  const float* ap = acb + bh * NCH;
  float h0 = 0.f, h1 = 0.f, h2 = 0.f, h3 = 0.f;
  for (int c = 0; c < NCH; c++) {
    bf16* pc = sp + (size_t)c * 4096;
    float s0 = __bfloat162float(pc[0]);
    float s1 = __bfloat162float(pc[256]);
    float s2 = __bfloat162float(pc[512]);
    float s3 = __bfloat162float(pc[768]);
    float a = ap[c];
    pc[0]   = __float2bfloat16(h0);
    pc[256] = __float2bfloat16(h1);
    pc[512] = __float2bfloat16(h2);
    pc[768] = __float2bfloat16(h3);
    h0 = fmaf(h0, a, s0); h1 = fmaf(h1, a, s1);
    h2 = fmaf(h2, a, s2); h3 = fmaf(h3, a, s3);
  }
}

// ---------------------------------------------------------------------------
// MFMA chunk scan, pass 3.
// ---------------------------------------------------------------------------
__global__ __launch_bounds__(256)
void scan_y_kernel(const bf16* __restrict__ xact, const float* __restrict__ dts,
                   const float* __restrict__ ldab, const bf16* __restrict__ Sbuf,
                   bf16* __restrict__ yfull)
{
  __shared__ __align__(16) bf16 Cs[64][72];
  __shared__ __align__(16) bf16 Bs[64][72];    // reused for M after G loop
  __shared__ __align__(16) bf16 XT[64][72];
  __shared__ __align__(16) bf16 HT[64][72];
  __shared__ float lsS[64], dtS[64];
  const int bid = blockIdx.x;
  const int bh = bid & 63, c = bid >> 6;
  const int b = bh >> 5, h = bh & 31;
  const int t0 = c * TC;
  const int tid = threadIdx.x;
  const int w = tid >> 6, lane = tid & 63;
  const int lr = lane & 15, lq = lane >> 4;

  if (w == 0) {
    float v = ldab[(size_t)(b * SEQ + t0 + lane) * NHEADS + h];
    #pragma unroll
    for (int o = 1; o < 64; o <<= 1) {
      float up = __shfl_up(v, o);
      if (lane >= o) v += up;
    }
    lsS[lane] = v;
    dtS[lane] = dts[(size_t)(b * SEQ + t0 + lane) * NHEADS + h];
  }
  {
    int nn = tid & 63, u0 = (tid >> 6) * 16;
    for (int i = 0; i < 16; i++) {
      int u = u0 + i;
      const bf16* rowp = xact + (size_t)(b * SEQ + t0 + u) * CONV_DIM;
      Bs[u][nn] = rowp[D_INNER + nn];
      Cs[u][nn] = rowp[D_INNER + 64 + nn];
      XT[nn][u] = rowp[h * 64 + nn];
    }
    const bf16* sb = Sbuf + ((size_t)bh * NCH + c) * 4096;
    for (int i = 0; i < 16; i++) {
      int e = tid + 256 * i;
      HT[e >> 6][e & 63] = sb[e];
    }
  }
  __syncthreads();

  bhalf8 cf0 = *(const bhalf8*)&Cs[16 * w + lr][lq * 8];
  bhalf8 cf1 = *(const bhalf8*)&Cs[16 * w + lr][32 + lq * 8];
  f32x4 accH[4];
  float mreg[4][4];
  #pragma unroll
  for (int jt = 0; jt < 4; jt++) {
    bhalf8 bf0 = *(const bhalf8*)&Bs[16 * jt + lr][lq * 8];
    bhalf8 bf1 = *(const bhalf8*)&Bs[16 * jt + lr][32 + lq * 8];
    f32x4 g = (f32x4){0.f, 0.f, 0.f, 0.f};
    g = __builtin_amdgcn_mfma_f32_16x16x32_bf16(cf0, bf0, g, 0, 0, 0);
    g = __builtin_amdgcn_mfma_f32_16x16x32_bf16(cf1, bf1, g, 0, 0, 0);
    bhalf8 hf0 = *(const bhalf8*)&HT[16 * jt + lr][lq * 8];
    bhalf8 hf1 = *(const bhalf8*)&HT[16 * jt + lr][32 + lq * 8];
    f32x4 ah = (f32x4){0.f, 0.f, 0.f, 0.f};
    ah = __builtin_amdgcn_mfma_f32_16x16x32_bf16(cf0, hf0, ah, 0, 0, 0);
    ah = __builtin_amdgcn_mfma_f32_16x16x32_bf16(cf1, hf1, ah, 0, 0, 0);
    accH[jt] = ah;
    #pragma unroll
    for (int r = 0; r < 4; r++) {
      int t = 16 * w + lq * 4 + r;
      int u = 16 * jt + lr;
      float m = 0.f;
      if (u <= t) m = g[r] * __expf(lsS[t] - lsS[u]) * dtS[u];
      mreg[jt][r] = m;
    }
  }
  __syncthreads();               // all Bs reads complete
  #pragma unroll
  for (int jt = 0; jt < 4; jt++)
    #pragma unroll
    for (int r = 0; r < 4; r++)
      Bs[16 * w + lq * 4 + r][16 * jt + lr] = __float2bfloat16(mreg[jt][r]);
  __syncthreads();

  bhalf8 mf0 = *(const bhalf8*)&Bs[16 * w + lr][lq * 8];
  bhalf8 mf1 = *(const bhalf8*)&Bs[16 * w + lr][32 + lq * 8];
  #pragma unroll
  for (int jt = 0; jt < 4; jt++) {
    bhalf8 xf0 = *(const bhalf8*)&XT[16 * jt + lr][lq * 8];
    bhalf8 xf1 = *(const bhalf8*)&XT[16 * jt + lr][32 + lq * 8];
    f32x4 acc = (f32x4){0.f, 0.f, 0.f, 0.f};
    acc = __builtin_amdgcn_mfma_f32_16x16x32_bf16(mf0, xf0, acc, 0, 0, 0);
    acc = __builtin_amdgcn_mfma_f32_16x16x32_bf16(mf1, xf1, acc, 0, 0, 0);
    #pragma unroll
    for (int r = 0; r < 4; r++) {
      int t = 16 * w + lq * 4 + r;
      int p = 16 * jt + lr;
      float y = acc[r] + __expf(lsS[t]) * accH[jt][r];
      yfull[(size_t)(b * SEQ + t0 + t) * D_INNER + h * 64 + p] = __float2bfloat16(y);
    }
  }
}

// ---------------------------------------------------------------------------
// y = yfull + D*x;  y *= silu(z);  RMSNorm * norm_w -> bf16.
// ---------------------------------------------------------------------------
__global__ __launch_bounds__(256)
void gate_rms_kernel(const bf16* __restrict__ yfull, const bf16* __restrict__ xact,
                     const bf16* __restrict__ zxb, const bf16* __restrict__ Dp,
                     const bf16* __restrict__ nw, bf16* __restrict__ yn)
{
  int row = blockIdx.x, t = threadIdx.x;
  int c0 = t * 8;
  __shared__ float rq[4];
  bhalf8 yv8 = *(const bhalf8*)(yfull + (size_t)row * D_INNER + c0);
  bhalf8 xv8 = *(const bhalf8*)(xact + (size_t)row * CONV_DIM + c0);
  bhalf8 zv8 = *(const bhalf8*)(zxb + (size_t)row * D_IN_PROJ + c0);
  float Dv = __bfloat162float(Dp[c0 >> 6]);
  float yv[8]; float ss = 0.f;
  #pragma unroll
  for (int j = 0; j < 8; j++) {
    float y = (float)yv8[j] + Dv * (float)xv8[j];
    float z = (float)zv8[j];
    yv[j] = y * (z / (1.f + expf(-z)));
    ss += yv[j] * yv[j];
  }
  #pragma unroll
  for (int o = 32; o; o >>= 1) ss += __shfl_down(ss, o);
  if ((t & 63) == 0) rq[t >> 6] = ss;
  __syncthreads();
  float tot = rq[0] + rq[1] + rq[2] + rq[3];
  float rr = rsqrtf(tot * (1.f / D_INNER) + 1e-5f);
  bhalf8 nv8 = *(const bhalf8*)(nw + c0);
  bhalf8 o;
  #pragma unroll
  for (int j = 0; j < 8; j++)
    o[j] = (bhalf)(yv[j] * rr * (float)nv8[j]);
  *(bhalf8*)(yn + (size_t)row * D_INNER + c0) = o;
}

// ---------------------------------------------------------------------------
extern "C" void kernel_launch(void* const* d_in, const int* in_sizes, int n_in,
                              void* d_out, int out_size, void* d_ws, size_t ws_size,
                              hipStream_t stream)
{
  char* ws = (char*)d_ws;
  bf16*  x1b   = (bf16*) (ws + 0);           //  [3->4]
  bf16*  Sbuf  = (bf16*) (ws + 0);           //  [7->9]   alias x1b (dead @4)
  bf16*  ynb   = (bf16*) (ws + 0);           //  [10->11] alias Sbuf
  float* pf0   = (float*)(ws + 0);           //  [14->14b] alias ynb
  bf16*  wproj = (bf16*) (ws + 16777216);    //  [2->4]
  float* acb   = (float*)(ws + 16777216);    //  [7->8]   alias wproj
  float* dtsb  = (float*)(ws + 16785408);    //  [5->9]   alias wproj
  float* ldab  = (float*)(ws + 17309696);    //  [5->9]   alias wproj
  float* pf1   = (float*)(ws + 16777216);    //  [14->14b] alias wproj region
  bf16*  wout  = (bf16*) (ws + 25493504);    //  [2->11]
  bf16*  w1c   = (bf16*) (ws + 29687808);    //  [2->13]
  bf16*  w2c   = (bf16*) (ws + 38076416);    //  [2->14]
  bf16*  ln0w  = (bf16*) (ws + 46465024);
  bf16*  ln0b  = (bf16*) (ws + 46467072);
  bf16*  ln1w  = (bf16*) (ws + 46469120);
  bf16*  ln1b  = (bf16*) (ws + 46471168);
  bf16*  ln2w  = (bf16*) (ws + 46473216);
  bf16*  ln2b  = (bf16*) (ws + 46475264);
  bf16*  convw = (bf16*) (ws + 46477312);
  bf16*  convb = (bf16*) (ws + 46494720);
  bf16*  dtb   = (bf16*) (ws + 46499072);
  bf16*  alog  = (bf16*) (ws + 46499136);
  bf16*  Dp    = (bf16*) (ws + 46499200);
  bf16*  normw = (bf16*) (ws + 46499264);
  bf16*  b1c   = (bf16*) (ws + 46503360);
  bf16*  b2c   = (bf16*) (ws + 46511552);
  int*   flag  = (int*)  (ws + 46513600);
  bf16*  x0b   = (bf16*) (ws + 46514176);    //  [3->11b]
  bf16*  zxb   = (bf16*) (ws + 54902784);    //  [4->10]
  float* x2f   = (float*)(ws + 54902784);    //  [11b->14b] alias zxb (ends 71.68M)
  float* pf3   = (float*)(ws + 71680000);    //  [14->14b] zxb tail (dead @10), ends 88.46M
  bf16*  xact  = (bf16*) (ws + 89767936);    //  [5->10]
  float* pout0 = (float*)(ws + 89767936);    //  [11->11b] alias xact
  float* pout1 = (float*)(ws + 106545152);   //  [11->11b]
  bf16*  gbuf  = (bf16*) (ws + 89767936);    //  [13->14] alias xact region
  bf16*  yfull = (bf16*) (ws + 125419520);   //  [9->10]
  bf16*  hln   = (bf16*) (ws + 125419520);   //  [11b->13] alias yfull
  float* pf2   = (float*)(ws + 125419520);   //  [14->14b] alias hln (dead @13)

  CvtArgs ca;
  void* dsts[NT] = { ln0w, ln0b, ln1w, ln1b, ln2w, ln2b, wproj, convw, convb,
                     dtb, alog, Dp, normw, wout, w1c, b1c, w2c, b2c };
  int cc = 0;
  ca.ccum[0] = 0;
  for (int i = 0; i < NT; i++) {
    ca.src[i] = d_in[i + 1];
    ca.dst[i] = dsts[i];
    ca.nel[i] = in_sizes[i + 1];
    cc += (in_sizes[i + 1] + 2047) / 2048;
    ca.ccum[i + 1] = cc;
  }
  cvt_kernel<<<cc, 256, 0, stream>>>(ca, (const unsigned short*)d_in[0], flag);

  ln01_kernel<<<NROWS, 256, 0, stream>>>(d_in[0], flag, ln0w, ln0b, ln1w, ln1b,
                                         x0b, x1b);

  // in_proj main: BK=32 128^2 dbuf counted, 4 blocks/CU (1024 blocks).
  // Tail (cols 4096..4255) on the BK=64 128^2 kernel.
  gemm128_bk32<0><<<dim3(32, 32), 256, 0, stream>>>(x1b, wproj, NROWS, 4096, D_MODEL,
                                                    D_IN_PROJ, zxb, nullptr);
  gemm_bt<0><<<dim3(2, 32), 256, 0, stream>>>(x1b, wproj + (size_t)4096 * D_MODEL,
                                              NROWS, 160, D_MODEL, D_IN_PROJ,
                                              zxb + 4096, nullptr);

  conv_silu_dt_kernel<<<dim3(2, NROWS), 256, 0, stream>>>(zxb, convw, convb, xact,
                                                          dtb, alog, dtsb, ldab);

  scan_state_kernel<<<NCH * 64, 256, 0, stream>>>(xact, dtsb, ldab, Sbuf, acb);
  state_prop_kernel<<<64 * 4, 256, 0, stream>>>(Sbuf, acb);
  scan_y_kernel<<<NCH * 64, 256, 0, stream>>>(xact, dtsb, ldab, Sbuf, yfull);

  gate_rms_kernel<<<NROWS, 256, 0, stream>>>(yfull, xact, zxb, Dp, normw, ynb);

  // out_proj: 64x128 split-K=2 -> partials, then fused reduce+residual+ln2
  SkParts4 po = { { pout0, pout1, pout0, pout0 } };
  gemm_skinny_sk<2><<<1024, 256, 0, stream>>>(ynb, wout, NROWS, D_MODEL, D_INNER, po);
  reduce_out_ln2_kernel<<<NROWS, 256, 0, stream>>>(pout0, pout1, x0b, x2f,
                                                   ln2w, ln2b, hln);

  // ffn1: moved onto the round-5 winner — BK=32 128^2, 4 blocks/CU.
  gemm128_bk32<2><<<dim3(32, 32), 256, 0, stream>>>(hln, w1c, NROWS, FFN_DIM, D_MODEL,
                                                    FFN_DIM, gbuf, b1c);

  // ffn2: 64x128 split-K=4 (2048 blocks, 8/CU) -> partials, then fused reduce
  SkParts4 pfp = { { pf0, pf1, pf2, pf3 } };
  gemm_skinny_sk<4><<<2048, 256, 0, stream>>>(gbuf, w2c, NROWS, D_MODEL, FFN_DIM, pfp);
  reduce_ffn_kernel<<<(NROWS * D_MODEL) / 1024, 256, 0, stream>>>(pf0, pf1, pf2, pf3,
                                                                  b2c, x2f, d_out, flag);
}